// Round 9
// baseline (1749.632 us; speedup 1.0000x reference)
//
#include <hip/hip_runtime.h>
#include <stdint.h>
#include <stdio.h>

#define T_TOK 8192
#define HDIM  1024
#define IDIM  3584
#define NEXP  8
#define NPAIR (T_TOK*2)
#define BM 128
#define BN 128
#define BK 32

typedef float          f32x4 __attribute__((ext_vector_type(4)));
typedef short          s16x8 __attribute__((ext_vector_type(8)));
typedef unsigned short u16x4 __attribute__((ext_vector_type(4)));
typedef unsigned short u16x8 __attribute__((ext_vector_type(8)));

__device__ __forceinline__ unsigned short f2bf_rne(float f) {
  unsigned u = __float_as_uint(f);
  u += 0x7FFFu + ((u >> 16) & 1u);
  return (unsigned short)(u >> 16);
}
__device__ __forceinline__ float bf2f(unsigned short h) {
  return __uint_as_float(((unsigned)h) << 16);
}

__device__ __forceinline__ void gld16(const void* gsrc, void* ldst) {
  typedef const unsigned int __attribute__((address_space(1))) GU;
  typedef unsigned int       __attribute__((address_space(3))) LU;
  __builtin_amdgcn_global_load_lds((GU*)(unsigned long long)gsrc,
                                   (LU*)(unsigned int)(unsigned long long)ldst,
                                   16, 0, 0);
}

// ================= K1: split f32 -> (hi, lo) bf16 =================
__global__ void split_hilo(const float* __restrict__ in,
                           unsigned short* __restrict__ hi,
                           unsigned short* __restrict__ lo, int n4) {
  int i = blockIdx.x*blockDim.x + threadIdx.x;
  int s = gridDim.x*blockDim.x;
  for (; i < n4; i += s) {
    f32x4 v = ((const f32x4*)in)[i];
    u16x4 h, l;
#pragma unroll
    for (int j = 0; j < 4; j++) {
      float f = v[j];
      unsigned short hb = f2bf_rne(f);
      h[j] = hb;
      l[j] = f2bf_rne(f - bf2f(hb));
    }
    ((u16x4*)hi)[i] = h;
    ((u16x4*)lo)[i] = l;
  }
}

// ===== K2: transpose W [E][K][N] f32 -> Wt [E][N][K] bf16 hi (+lo optional)
__global__ void transpose_split(const float* __restrict__ W,
                                unsigned short* __restrict__ hi,
                                unsigned short* __restrict__ lo,
                                int K, int N) {
  __shared__ float tile[32][33];
  long base = (long)blockIdx.z * K * N;
  int n0 = blockIdx.x*32, k0 = blockIdx.y*32;
  int tx = threadIdx.x, ty = threadIdx.y; // 32 x 8
#pragma unroll
  for (int r = 0; r < 4; r++)
    tile[ty+8*r][tx] = W[base + (long)(k0+ty+8*r)*N + n0 + tx];
  __syncthreads();
#pragma unroll
  for (int r = 0; r < 4; r++) {
    float f = tile[tx][ty+8*r];
    long o = base + (long)(n0+ty+8*r)*K + k0 + tx;
    unsigned short hb = f2bf_rne(f);
    hi[o] = hb;
    if (lo) lo[o] = f2bf_rne(f - bf2f(hb));
  }
}

// ---- shared top-2 helper (stable, lowest-index tie-break like lax.top_k)
__device__ __forceinline__ void top2_write(const float* acc, int t,
                                           int* __restrict__ topi,
                                           float* __restrict__ topw) {
  int i0 = 0; float l0 = acc[0];
#pragma unroll
  for (int e = 1; e < NEXP; e++) if (acc[e] > l0) { l0 = acc[e]; i0 = e; }
  int i1 = -1; float l1 = -3.4e38f;
#pragma unroll
  for (int e = 0; e < NEXP; e++) if (e != i0 && acc[e] > l1) { l1 = acc[e]; i1 = e; }
  float w0 = 1.f/(1.f + expf(l1 - l0));
  float w1 = 1.f/(1.f + expf(l0 - l1));
  topi[2*t]   = i0; topi[2*t+1] = i1;
  topw[2*t]   = w0; topw[2*t+1] = w1;
}

// ===== K3: fused gate+up router (one pass over x) =========================
__global__ __launch_bounds__(256) void router2_topk(
    const float* __restrict__ X,
    const float* __restrict__ RWg, const float* __restrict__ RWu,
    int* __restrict__ tig, float* __restrict__ twg,
    int* __restrict__ tiu, float* __restrict__ twu) {
  int lane = threadIdx.x & 63;
  int t = blockIdx.x*4 + (threadIdx.x>>6);
  const f32x4* xr = (const f32x4*)(X + (long)t*HDIM);
  float ag[NEXP], au[NEXP];
#pragma unroll
  for (int e = 0; e < NEXP; e++) { ag[e] = 0.f; au[e] = 0.f; }
#pragma unroll
  for (int it = 0; it < HDIM/4/64; it++) {   // 4
    int c4 = it*64 + lane;
    f32x4 xv = xr[c4];
#pragma unroll
    for (int j = 0; j < 4; j++) {
      const float* wg = RWg + (long)(c4*4+j)*NEXP;
      const float* wu = RWu + (long)(c4*4+j)*NEXP;
#pragma unroll
      for (int e = 0; e < NEXP; e++) { ag[e] += xv[j]*wg[e]; au[e] += xv[j]*wu[e]; }
    }
  }
#pragma unroll
  for (int e = 0; e < NEXP; e++) {
    float vg = ag[e], vu = au[e];
#pragma unroll
    for (int o = 1; o < 64; o <<= 1) { vg += __shfl_xor(vg, o); vu += __shfl_xor(vu, o); }
    ag[e] = vg; au[e] = vu;
  }
  if (lane == 0) { top2_write(ag, t, tig, twg); top2_write(au, t, tiu, twu); }
}

// ===== K4: deterministic stable per-expert compaction (1 block per expert)
__global__ __launch_bounds__(256) void build_perm(const int* __restrict__ topi,
                                                  const float* __restrict__ topw,
                                                  int* __restrict__ offs,
                                                  int* __restrict__ ptok,
                                                  float* __restrict__ pw) {
  int e = blockIdx.x;
  int tid = threadIdx.x, lane = tid & 63, wv = tid >> 6;
  __shared__ int cnt[NEXP];
  __shared__ int wsum[4];
  if (tid < NEXP) cnt[tid] = 0;
  __syncthreads();
  for (int p = tid; p < NPAIR; p += 256) atomicAdd(&cnt[topi[p]], 1);
  __syncthreads();
  int base = 0;
#pragma unroll
  for (int e2 = 0; e2 < NEXP; e2++) if (e2 < e) base += cnt[e2];
  if (tid == 0) { offs[e] = base; if (e == NEXP-1) offs[NEXP] = base + cnt[e]; }
  for (int p0 = 0; p0 < NPAIR; p0 += 256) {
    int p = p0 + tid;
    bool m = (topi[p] == e);
    unsigned long long b = __ballot(m);
    int lp = __popcll(b & ((1ull << lane) - 1ull));
    if (lane == 0) wsum[wv] = __popcll(b);
    __syncthreads();
    int woff = 0;
#pragma unroll
    for (int w2 = 0; w2 < 4; w2++) if (w2 < wv) woff += wsum[w2];
    int tot = wsum[0] + wsum[1] + wsum[2] + wsum[3];
    if (m) { int dst = base + woff + lp; ptok[dst] = p >> 1; pw[dst] = topw[p]; }
    base += tot;
    __syncthreads();
  }
}

// ===== K5: gathered 3-term GEMM, 256x128 tile, counted-vmcnt pipeline =====
// Macro-tile memory pattern kept from round 8 (all 4 planes per K-step, each
// plane streamed once per block -> L2-friendly; FETCH 474MB verified).
// NEW (T3/T4): TRIPLE-buffered LDS (3 x 48KB = 144KB); tile t issues the 6
// gld16 for tile t+2, computes from buf[t%3], then waits vmcnt(6) -- retiring
// exactly tile t+1's 6 loads (in-order vmcnt semantics, m135) while t+2's
// stay in flight ACROSS the barrier. Never drains to 0 in steady state
// (m218: counted-vs-drain0 = +38-73%). 3 term phases (hi*hi, hi*lo, lo*hi)
// in the same order as round 8 -> bit-identical accumulation.
__global__ __launch_bounds__(512) void moe_gemm3_cv(
    const unsigned short* __restrict__ Ahi, const unsigned short* __restrict__ Alo,
    const unsigned short* __restrict__ Bhi, const unsigned short* __restrict__ Blo,
    const int* __restrict__ offs, const int* __restrict__ ptok,
    const float* __restrict__ pw, float* __restrict__ out)
{
  const int NT = HDIM/BK;              // 32 K-tiles
  const int e = blockIdx.z;
  const int beg = offs[e];
  const int cnt = offs[e+1] - beg;
  const int m0 = blockIdx.y * 256;     // BM=256 rows; NO XCD swizzle
  if (m0 >= cnt) return;
  const int n0 = blockIdx.x * 128;     // BN=128 cols

  __shared__ unsigned short As[3][2][256*32];  // 96 KB
  __shared__ unsigned short Bs[3][2][128*32];  // 48 KB
  __shared__ int   stok[256];
  __shared__ float swt[256];

  const int tid = threadIdx.x, lane = tid & 63, wv = tid >> 6;
  if (tid < 256) {
    int i = m0 + tid;
    stok[tid] = ptok[beg + (i < cnt ? i : 0)];
    swt[tid]  = (i < cnt) ? pw[beg + i] : 0.f;
  }
  __syncthreads();

  // staging geometry (pre-swizzled source, verified 0-conflict):
  // phys 16B chunk p of row r holds logical chunk (p - (r>>1)) & 3.
  const int srow = lane >> 2;                              // 0..15
  const int lc   = ((lane & 3) - ((lane >> 3) & 3)) & 3;   // logical chunk
  // A: wave wv stages rows [wv*32, wv*32+32) as two 16-row slabs (x2 planes)
  const long aoff0 = (long)stok[wv*32 +      srow]*HDIM + lc*8;
  const long aoff1 = (long)stok[wv*32 + 16 + srow]*HDIM + lc*8;
  // B: wave wv stages rows [wv*16, wv*16+16) (x2 planes)
  const long boff  = ((long)e*IDIM + n0 + wv*16 + srow)*HDIM + lc*8;
  const int dstA0 = (wv*32     )*32;   // shorts
  const int dstA1 = (wv*32 + 16)*32;
  const int dstB  = (wv*16     )*32;

#define STAGE(buf, kk) do {                                  \
    int kl_ = (kk)*32;                                       \
    gld16(Ahi + aoff0 + kl_, &As[buf][0][dstA0]);            \
    gld16(Ahi + aoff1 + kl_, &As[buf][0][dstA1]);            \
    gld16(Alo + aoff0 + kl_, &As[buf][1][dstA0]);            \
    gld16(Alo + aoff1 + kl_, &As[buf][1][dstA1]);            \
    gld16(Bhi + boff  + kl_, &Bs[buf][0][dstB]);             \
    gld16(Blo + boff  + kl_, &Bs[buf][1][dstB]);             \
  } while (0)

  // read-side: lane reads logical k-chunk fg at phys (fg+(fl>>1))&3
  const int fl = lane & 15, fg = lane >> 4;
  const int pks = (((fg + (fl >> 1)) & 3) << 3);
  const int wm = wv >> 1, wn = wv & 1;      // 4M x 2N wave grid, 64x64/wave
  const int arow = wm * 64;
  const int bcol = wn * 64;

  f32x4 acc[4][4];
#pragma unroll
  for (int m = 0; m < 4; m++)
#pragma unroll
    for (int n = 0; n < 4; n++) acc[m][n] = {0.f, 0.f, 0.f, 0.f};

  // prologue: stage tiles 0,1; wait for tile 0 only (vmcnt(6) of 12)
  STAGE(0, 0);
  STAGE(1, 1);
  asm volatile("s_waitcnt vmcnt(6)" ::: "memory");
  __builtin_amdgcn_s_barrier();
  __builtin_amdgcn_sched_barrier(0);

  int cur = 0;
  for (int kt = 0; kt < NT; ++kt) {
    const int nxt2 = (cur + 2 >= 3) ? cur - 1 : cur + 2;
    const bool st = (kt + 2 < NT);
    if (st) STAGE(nxt2, kt + 2);     // depth-2 prefetch, in flight 2 tiles

    s16x8 ahi[4], bhi[4], bx[4];
    // phase 1: hi*hi
#pragma unroll
    for (int i = 0; i < 4; i++)
      ahi[i] = *(const s16x8*)&As[cur][0][(arow + i*16 + fl)*32 + pks];
#pragma unroll
    for (int n = 0; n < 4; n++)
      bhi[n] = *(const s16x8*)&Bs[cur][0][(bcol + n*16 + fl)*32 + pks];
    __builtin_amdgcn_s_setprio(1);
#pragma unroll
    for (int i = 0; i < 4; i++)
#pragma unroll
      for (int n = 0; n < 4; n++)
        acc[i][n] = __builtin_amdgcn_mfma_f32_16x16x32_bf16(ahi[i], bhi[n], acc[i][n], 0,0,0);
    __builtin_amdgcn_s_setprio(0);

    // phase 2: hi*lo (ahi live)
#pragma unroll
    for (int n = 0; n < 4; n++)
      bx[n] = *(const s16x8*)&Bs[cur][1][(bcol + n*16 + fl)*32 + pks];
    __builtin_amdgcn_s_setprio(1);
#pragma unroll
    for (int i = 0; i < 4; i++)
#pragma unroll
      for (int n = 0; n < 4; n++)
        acc[i][n] = __builtin_amdgcn_mfma_f32_16x16x32_bf16(ahi[i], bx[n], acc[i][n], 0,0,0);
    __builtin_amdgcn_s_setprio(0);

    // phase 3: lo*hi (bhi live; alo overwrites ahi)
#pragma unroll
    for (int i = 0; i < 4; i++)
      ahi[i] = *(const s16x8*)&As[cur][1][(arow + i*16 + fl)*32 + pks];
    __builtin_amdgcn_s_setprio(1);
#pragma unroll
    for (int i = 0; i < 4; i++)
#pragma unroll
      for (int n = 0; n < 4; n++)
        acc[i][n] = __builtin_amdgcn_mfma_f32_16x16x32_bf16(ahi[i], bhi[n], acc[i][n], 0,0,0);
    __builtin_amdgcn_s_setprio(0);

    // tile end: counted drain — retire exactly tile t+1's 6 loads;
    // tile t+2's 6 stay in flight across the barrier (T4).
    if (st) asm volatile("s_waitcnt vmcnt(6)" ::: "memory");
    else    asm volatile("s_waitcnt vmcnt(0)" ::: "memory");
    __builtin_amdgcn_s_barrier();
    __builtin_amdgcn_sched_barrier(0);

    cur = (cur + 1 >= 3) ? 0 : cur + 1;
  }
#undef STAGE

  // epilogue: C/D map col=lane&15, row=(lane>>4)*4+r  [m89/m91-verified]
#pragma unroll
  for (int m = 0; m < 4; m++)
#pragma unroll
    for (int r = 0; r < 4; r++) {
      int lrow = arow + m*16 + fg*4 + r;
      if (m0 + lrow < cnt) {
        float wt = swt[lrow];
        long ob = (long)stok[lrow]*IDIM + n0 + bcol + fl;
#pragma unroll
        for (int n = 0; n < 4; n++)
          atomicAdd(&out[ob + n*16], wt * acc[m][n][r]);
      }
    }
}

// ===== K6: fused SwiGLU + down-router (h in-place into g, one pass) =======
__global__ __launch_bounds__(256) void swiglu_router(
    float* __restrict__ g, const float* __restrict__ u,
    const float* __restrict__ RW,           // down router [IDIM][NEXP]
    int* __restrict__ topi, float* __restrict__ topw) {
  int lane = threadIdx.x & 63;
  int t = blockIdx.x*4 + (threadIdx.x>>6);
  f32x4*       gr = (f32x4*)(g + (long)t*IDIM);
  const f32x4* ur = (const f32x4*)(u + (long)t*IDIM);
  float acc[NEXP];
#pragma unroll
  for (int e = 0; e < NEXP; e++) acc[e] = 0.f;
#pragma unroll
  for (int it = 0; it < IDIM/4/64; it++) {   // 14
    int c4 = it*64 + lane;
    f32x4 gv = gr[c4], uv = ur[c4], hv;
#pragma unroll
    for (int j = 0; j < 4; j++) {
      float x = gv[j];
      hv[j] = x * uv[j] / (1.f + expf(-x));
    }
    gr[c4] = hv;
#pragma unroll
    for (int j = 0; j < 4; j++) {
      const float* wr = RW + (long)(c4*4+j)*NEXP;
#pragma unroll
      for (int e = 0; e < NEXP; e++) acc[e] += hv[j]*wr[e];
    }
  }
#pragma unroll
  for (int e = 0; e < NEXP; e++) {
    float v = acc[e];
#pragma unroll
    for (int o = 1; o < 64; o <<= 1) v += __shfl_xor(v, o);
    acc[e] = v;
  }
  if (lane == 0) top2_write(acc, t, topi, topw);
}

// ===== K7: down GEMM, 1-term: A = bf16(h), B = Wd_hi bf16 (unchanged) =====
__global__ __launch_bounds__(256) void moe_gemm_down(
    const float* __restrict__ Hf, const unsigned short* __restrict__ Bw,
    const int* __restrict__ offs, const int* __restrict__ ptok,
    const float* __restrict__ pw, float* __restrict__ out)
{
  const int K = IDIM, N = HDIM;
  const int e = blockIdx.z;
  const int beg = offs[e];
  const int cnt = offs[e+1] - beg;
  const int m0 = blockIdx.y * BM;   // NO swizzle
  if (m0 >= cnt) return;
  const int n0 = blockIdx.x * BN;

  __shared__ unsigned short Ah[BM*BK], Bh[BN*BK];
  __shared__ int   stok[BM];
  __shared__ float swt[BM];

  const int tid = threadIdx.x, lane = tid & 63, wv = tid >> 6;
  if (tid < BM) {
    int i = m0 + tid;
    stok[tid] = ptok[beg + (i < cnt ? i : 0)];
    swt[tid]  = (i < cnt) ? pw[beg + i] : 0.f;
  }
  __syncthreads();

  const int arw = tid >> 1, half = tid & 1;
  const float* asrc = Hf + (long)stok[arw]*K + half*16;
  const int awoff = arw*BK + half*16;

  const int srow = lane >> 2, scol = (lane & 3)*8;
  const int r0 = (wv*2+0)*16 + srow, r1 = (wv*2+1)*16 + srow;
  const long b0 = ((long)e*N + n0 + r0)*K + scol;
  const long b1 = ((long)e*N + n0 + r1)*K + scol;
  unsigned short* dB0 = &Bh[(wv*2+0)*16*BK];
  unsigned short* dB1 = &Bh[(wv*2+1)*16*BK];

  f32x4 zero = {0.f,0.f,0.f,0.f};
  f32x4 acc[4][4];
#pragma unroll
  for (int i = 0; i < 4; i++)
#pragma unroll
    for (int j = 0; j < 4; j++) acc[i][j] = zero;

  const int arow = (wv>>1)*64, bcol = (wv&1)*64;
  const int fl = lane & 15, fg = lane >> 4;

  f32x4 p0, p1, p2, p3;
#define LOADA(kk) do {                        \
    p0 = ((const f32x4*)(asrc + (kk)))[0];    \
    p1 = ((const f32x4*)(asrc + (kk)))[1];    \
    p2 = ((const f32x4*)(asrc + (kk)))[2];    \
    p3 = ((const f32x4*)(asrc + (kk)))[3];    \
  } while (0)

  LOADA(0);

  for (int kk = 0; kk < K; kk += BK) {
    __syncthreads();
    gld16(Bw + b0 + kk, dB0);
    gld16(Bw + b1 + kk, dB1);
    u16x8 ha, hb2;
    ha[0]=f2bf_rne(p0[0]); ha[1]=f2bf_rne(p0[1]); ha[2]=f2bf_rne(p0[2]); ha[3]=f2bf_rne(p0[3]);
    ha[4]=f2bf_rne(p1[0]); ha[5]=f2bf_rne(p1[1]); ha[6]=f2bf_rne(p1[2]); ha[7]=f2bf_rne(p1[3]);
    hb2[0]=f2bf_rne(p2[0]); hb2[1]=f2bf_rne(p2[1]); hb2[2]=f2bf_rne(p2[2]); hb2[3]=f2bf_rne(p2[3]);
    hb2[4]=f2bf_rne(p3[0]); hb2[5]=f2bf_rne(p3[1]); hb2[6]=f2bf_rne(p3[2]); hb2[7]=f2bf_rne(p3[3]);
    *(u16x8*)&Ah[awoff]   = ha;
    *(u16x8*)&Ah[awoff+8] = hb2;
    asm volatile("s_waitcnt vmcnt(0)" ::: "memory");
    __syncthreads();

    if (kk + BK < K) LOADA(kk + BK);

    s16x8 ahf[4], bhf[4];
#pragma unroll
    for (int i = 0; i < 4; i++) {
      ahf[i] = *(const s16x8*)&Ah[(arow + i*16 + fl)*BK + fg*8];
      bhf[i] = *(const s16x8*)&Bh[(bcol + i*16 + fl)*BK + fg*8];
    }
#pragma unroll
    for (int i = 0; i < 4; i++)
#pragma unroll
      for (int j = 0; j < 4; j++)
        acc[i][j] = __builtin_amdgcn_mfma_f32_16x16x32_bf16(ahf[i], bhf[j], acc[i][j], 0,0,0);
  }
#undef LOADA

#pragma unroll
  for (int i = 0; i < 4; i++)
#pragma unroll
    for (int r = 0; r < 4; r++) {
      int lrow = arow + i*16 + fg*4 + r;
      if (m0 + lrow < cnt) {
        float wt = swt[lrow];
        long ob = (long)stok[lrow]*N + n0 + bcol + fl;
#pragma unroll
        for (int j = 0; j < 4; j++)
          atomicAdd(&out[ob + j*16], wt * acc[i][j][r]);
      }
    }
}

// ========================== host launcher =================================
// Workspace aliasing (448 MiB avail, peak ~387 MB):
//   ubuf  aliases [wg_hi, wg_lo] — first written AFTER gate GEMM (last wg reader)
//   wd_hi aliases [wu_hi, ...]   — transposed AFTER up GEMM (last wu reader)
extern "C" void kernel_launch(void* const* d_in, const int* in_sizes, int n_in,
                              void* d_out, int out_size, void* d_ws, size_t ws_size,
                              hipStream_t stream)
{
  (void)in_sizes; (void)n_in;
  const float* x   = (const float*)d_in[0];
  const float* grt = (const float*)d_in[1];
  const float* gex = (const float*)d_in[2];
  const float* urt = (const float*)d_in[3];
  const float* uex = (const float*)d_in[4];
  const float* drt = (const float*)d_in[5];
  const float* dex = (const float*)d_in[6];
  float* out = (float*)d_out;

  char* base = (char*)d_ws;
  size_t off = 0;
  auto alloc = [&](size_t b) -> void* {
    void* r = base + off;
    off = (off + b + 255) & ~(size_t)255;
    return r;
  };
  const size_t szXH = (size_t)T_TOK*HDIM*2;
  const size_t szW  = (size_t)NEXP*HDIM*IDIM*2;
  const size_t szGI = (size_t)T_TOK*IDIM*4;

  unsigned short* xhi   = (unsigned short*)alloc(szXH);
  unsigned short* xlo   = (unsigned short*)alloc(szXH);
  unsigned short* wg_hi = (unsigned short*)alloc(szW);   // later: ubuf (f32)
  unsigned short* wg_lo = (unsigned short*)alloc(szW);
  unsigned short* wu_hi = (unsigned short*)alloc(szW);   // later: wd_hi
  unsigned short* wu_lo = (unsigned short*)alloc(szW);
  float* gbuf = (float*)alloc(szGI);
  int*   topi_g = (int*)alloc(NPAIR*4);  float* topw_g = (float*)alloc(NPAIR*4);
  int*   topi_u = (int*)alloc(NPAIR*4);  float* topw_u = (float*)alloc(NPAIR*4);
  int*   topi_d = (int*)alloc(NPAIR*4);  float* topw_d = (float*)alloc(NPAIR*4);
  int* offs_g = (int*)alloc(64);
  int* offs_u = (int*)alloc(64);
  int* offs_d = (int*)alloc(64);
  int*   ptok_g = (int*)alloc(NPAIR*4);  float* pw_g = (float*)alloc(NPAIR*4);
  int*   ptok_u = (int*)alloc(NPAIR*4);  float* pw_u = (float*)alloc(NPAIR*4);
  int*   ptok_d = (int*)alloc(NPAIR*4);  float* pw_d = (float*)alloc(NPAIR*4);

  float*          ubuf  = (float*)wg_hi;
  unsigned short* wd_hi = wu_hi;

  if (off > ws_size) {
    fprintf(stderr, "[moe] ws too small: need %zu bytes, have %zu\n", off, ws_size);
    hipMemsetAsync(d_out, 0, (size_t)out_size*sizeof(float), stream);
    return;
  }

  hipMemsetAsync(gbuf, 0, szGI, stream);
  hipMemsetAsync(d_out, 0, (size_t)out_size*sizeof(float), stream);

  split_hilo<<<2048, 256, 0, stream>>>(x, xhi, xlo, T_TOK*HDIM/4);
  transpose_split<<<dim3(IDIM/32, HDIM/32, NEXP), dim3(32,8), 0, stream>>>(gex, wg_hi, wg_lo, HDIM, IDIM);
  transpose_split<<<dim3(IDIM/32, HDIM/32, NEXP), dim3(32,8), 0, stream>>>(uex, wu_hi, wu_lo, HDIM, IDIM);
  router2_topk<<<T_TOK/4, 256, 0, stream>>>(x, grt, urt, topi_g, topw_g, topi_u, topw_u);
  build_perm<<<NEXP, 256, 0, stream>>>(topi_g, topw_g, offs_g, ptok_g, pw_g);
  build_perm<<<NEXP, 256, 0, stream>>>(topi_u, topw_u, offs_u, ptok_u, pw_u);

  // gate GEMM (last reader of wg region): 256x128 tiles; y=32 covers cnt<=8192
  moe_gemm3_cv<<<dim3(IDIM/128, 32, NEXP), 512, 0, stream>>>(
      xhi, xlo, wg_hi, wg_lo, offs_g, ptok_g, pw_g, gbuf);

  // wg region dead -> ubuf
  hipMemsetAsync(ubuf, 0, szGI, stream);
  moe_gemm3_cv<<<dim3(IDIM/128, 32, NEXP), 512, 0, stream>>>(
      xhi, xlo, wu_hi, wu_lo, offs_u, ptok_u, pw_u, ubuf);

  // wu region dead -> wd_hi
  transpose_split<<<dim3(HDIM/32, IDIM/32, NEXP), dim3(32,8), 0, stream>>>(dex, wd_hi, nullptr, IDIM, HDIM);

  // fused: h = silu(g)*u in-place into gbuf + down-router top2
  swiglu_router<<<T_TOK/4, 256, 0, stream>>>(gbuf, ubuf, drt, topi_d, topw_d);
  build_perm<<<NEXP, 256, 0, stream>>>(topi_d, topw_d, offs_d, ptok_d, pw_d);

  moe_gemm_down<<<dim3(HDIM/BN, T_TOK/BM, NEXP), 256, 0, stream>>>(
      gbuf, wd_hi, offs_d, ptok_d, pw_d, out);
}

// Round 10
// 1620.652 us; speedup vs baseline: 1.0796x; 1.0796x over previous
//
#include <hip/hip_runtime.h>
#include <stdint.h>
#include <stdio.h>

#define T_TOK 8192
#define HDIM  1024
#define IDIM  3584
#define NEXP  8
#define NPAIR (T_TOK*2)
#define BK 32

typedef float          f32x4 __attribute__((ext_vector_type(4)));
typedef short          s16x8 __attribute__((ext_vector_type(8)));
typedef unsigned short u16x4 __attribute__((ext_vector_type(4)));
typedef unsigned short u16x8 __attribute__((ext_vector_type(8)));

__device__ __forceinline__ unsigned short f2bf_rne(float f) {
  unsigned u = __float_as_uint(f);
  u += 0x7FFFu + ((u >> 16) & 1u);
  return (unsigned short)(u >> 16);
}
__device__ __forceinline__ float bf2f(unsigned short h) {
  return __uint_as_float(((unsigned)h) << 16);
}

__device__ __forceinline__ void gld16(const void* gsrc, void* ldst) {
  typedef const unsigned int __attribute__((address_space(1))) GU;
  typedef unsigned int       __attribute__((address_space(3))) LU;
  __builtin_amdgcn_global_load_lds((GU*)(unsigned long long)gsrc,
                                   (LU*)(unsigned int)(unsigned long long)ldst,
                                   16, 0, 0);
}

// ---- shared top-2 helper (stable, lowest-index tie-break like lax.top_k)
__device__ __forceinline__ void top2_write(const float* acc, int t,
                                           int* __restrict__ topi,
                                           float* __restrict__ topw) {
  int i0 = 0; float l0 = acc[0];
#pragma unroll
  for (int e = 1; e < NEXP; e++) if (acc[e] > l0) { l0 = acc[e]; i0 = e; }
  int i1 = -1; float l1 = -3.4e38f;
#pragma unroll
  for (int e = 0; e < NEXP; e++) if (e != i0 && acc[e] > l1) { l1 = acc[e]; i1 = e; }
  float w0 = 1.f/(1.f + expf(l1 - l0));
  float w1 = 1.f/(1.f + expf(l0 - l1));
  topi[2*t]   = i0; topi[2*t+1] = i1;
  topw[2*t]   = w0; topw[2*t+1] = w1;
}

// ===== K1: FUSED x split (hi/lo) + gate/up routers (one pass over x) ======
__global__ __launch_bounds__(256) void split_router(
    const float* __restrict__ X,
    const float* __restrict__ RWg, const float* __restrict__ RWu,
    unsigned short* __restrict__ xhi, unsigned short* __restrict__ xlo,
    int* __restrict__ tig, float* __restrict__ twg,
    int* __restrict__ tiu, float* __restrict__ twu) {
  int lane = threadIdx.x & 63;
  int t = blockIdx.x*4 + (threadIdx.x>>6);
  const f32x4* xr = (const f32x4*)(X + (long)t*HDIM);
  u16x4* hr = (u16x4*)(xhi + (long)t*HDIM);
  u16x4* lr = (u16x4*)(xlo + (long)t*HDIM);
  float ag[NEXP], au[NEXP];
#pragma unroll
  for (int e = 0; e < NEXP; e++) { ag[e] = 0.f; au[e] = 0.f; }
#pragma unroll
  for (int it = 0; it < HDIM/4/64; it++) {   // 4
    int c4 = it*64 + lane;
    f32x4 xv = xr[c4];
    u16x4 hh, ll;
#pragma unroll
    for (int j = 0; j < 4; j++) {
      unsigned short hb = f2bf_rne(xv[j]);
      hh[j] = hb;
      ll[j] = f2bf_rne(xv[j] - bf2f(hb));
    }
    hr[c4] = hh; lr[c4] = ll;
#pragma unroll
    for (int j = 0; j < 4; j++) {
      const float* wg = RWg + (long)(c4*4+j)*NEXP;
      const float* wu = RWu + (long)(c4*4+j)*NEXP;
#pragma unroll
      for (int e = 0; e < NEXP; e++) { ag[e] += xv[j]*wg[e]; au[e] += xv[j]*wu[e]; }
    }
  }
#pragma unroll
  for (int e = 0; e < NEXP; e++) {
    float vg = ag[e], vu = au[e];
#pragma unroll
    for (int o = 1; o < 64; o <<= 1) { vg += __shfl_xor(vg, o); vu += __shfl_xor(vu, o); }
    ag[e] = vg; au[e] = vu;
  }
  if (lane == 0) { top2_write(ag, t, tig, twg); top2_write(au, t, tiu, twu); }
}

// ===== K2: vectorized transpose W [E][K][N] f32 -> Wt [E][N][K] bf16 ======
// block (8,32); loads f32x4/lane (16B), stores u16x4/lane (8B).
__global__ void transpose_split_v(const float* __restrict__ W,
                                  unsigned short* __restrict__ hi,
                                  unsigned short* __restrict__ lo,
                                  int K, int N) {
  __shared__ float t[32][33];
  long base = (long)blockIdx.z * K * N;
  int n0 = blockIdx.x*32, k0 = blockIdx.y*32;
  int id = threadIdx.y*8 + threadIdx.x;     // 0..255
  int lrr = id >> 3, lcq = id & 7;          // load: row 0..31, col-quad 0..7
  f32x4 v = *(const f32x4*)&W[base + (long)(k0+lrr)*N + n0 + lcq*4];
  t[lrr][lcq*4+0] = v[0]; t[lrr][lcq*4+1] = v[1];
  t[lrr][lcq*4+2] = v[2]; t[lrr][lcq*4+3] = v[3];
  __syncthreads();
  int n = threadIdx.y, kq = threadIdx.x;    // store: n 0..31, k-quad 0..7
  u16x4 h, l;
#pragma unroll
  for (int r = 0; r < 4; r++) {
    float f = t[kq*4+r][n];
    unsigned short hb = f2bf_rne(f);
    h[r] = hb;
    l[r] = f2bf_rne(f - bf2f(hb));
  }
  long o = base + (long)(n0+n)*K + k0 + kq*4;
  *(u16x4*)&hi[o] = h;
  if (lo) *(u16x4*)&lo[o] = l;
}

// ===== K4: deterministic stable per-expert compaction (1 block per expert)
__global__ __launch_bounds__(256) void build_perm(const int* __restrict__ topi,
                                                  const float* __restrict__ topw,
                                                  int* __restrict__ offs,
                                                  int* __restrict__ ptok,
                                                  float* __restrict__ pw) {
  int e = blockIdx.x;
  int tid = threadIdx.x, lane = tid & 63, wv = tid >> 6;
  __shared__ int cnt[NEXP];
  __shared__ int wsum[4];
  if (tid < NEXP) cnt[tid] = 0;
  __syncthreads();
  for (int p = tid; p < NPAIR; p += 256) atomicAdd(&cnt[topi[p]], 1);
  __syncthreads();
  int base = 0;
#pragma unroll
  for (int e2 = 0; e2 < NEXP; e2++) if (e2 < e) base += cnt[e2];
  if (tid == 0) { offs[e] = base; if (e == NEXP-1) offs[NEXP] = base + cnt[e]; }
  for (int p0 = 0; p0 < NPAIR; p0 += 256) {
    int p = p0 + tid;
    bool m = (topi[p] == e);
    unsigned long long b = __ballot(m);
    int lp = __popcll(b & ((1ull << lane) - 1ull));
    if (lane == 0) wsum[wv] = __popcll(b);
    __syncthreads();
    int woff = 0;
#pragma unroll
    for (int w2 = 0; w2 < 4; w2++) if (w2 < wv) woff += wsum[w2];
    int tot = wsum[0] + wsum[1] + wsum[2] + wsum[3];
    if (m) { int dst = base + woff + lp; ptok[dst] = p >> 1; pw[dst] = topw[p]; }
    base += tot;
    __syncthreads();
  }
}

// ===== K5: gathered 3-term GEMM, 256x256 MACRO-TILE (round-8 measured-best)
// + tweak: blo read up-front with bhi (saves 4 bhi re-reads; MFMA order and
// accumulation UNCHANGED -> bit-identical output).
__global__ __launch_bounds__(512) void moe_gemm3_mt(
    const unsigned short* __restrict__ Ahi, const unsigned short* __restrict__ Alo,
    const unsigned short* __restrict__ Bhi, const unsigned short* __restrict__ Blo,
    const int* __restrict__ offs, const int* __restrict__ ptok,
    const float* __restrict__ pw, float* __restrict__ out)
{
  const int e = blockIdx.z;
  const int beg = offs[e];
  const int cnt = offs[e+1] - beg;
  const int m0 = blockIdx.y * 256;   // NO XCD swizzle (round-3 lesson)
  if (m0 >= cnt) return;
  const int n0 = blockIdx.x * 256;

  __shared__ unsigned short As[2][2][256*32];  // [buf][hi/lo]  64KB
  __shared__ unsigned short Bs[2][2][256*32];  // 64KB
  __shared__ int   stok[256];
  __shared__ float swt[256];

  const int tid = threadIdx.x, lane = tid & 63, wv = tid >> 6;
  if (tid < 256) {
    int i = m0 + tid;
    stok[tid] = ptok[beg + (i < cnt ? i : 0)];
    swt[tid]  = (i < cnt) ? pw[beg + i] : 0.f;
  }
  __syncthreads();

  const int srow = lane >> 2;
  const int lc   = ((lane & 3) - ((lane >> 3) & 3)) & 3;  // pre-swizzled src
  const long aoff0 = (long)stok[wv*32 +      srow]*HDIM + lc*8;
  const long aoff1 = (long)stok[wv*32 + 16 + srow]*HDIM + lc*8;
  const long boff0 = ((long)e*IDIM + n0 + wv*32 +      srow)*HDIM + lc*8;
  const long boff1 = ((long)e*IDIM + n0 + wv*32 + 16 + srow)*HDIM + lc*8;
  const int dst0 = (wv*32     )*32;
  const int dst1 = (wv*32 + 16)*32;

#define STAGE_A(buf, kk) do {                                   \
    int kl_ = (kk)*32;                                          \
    gld16(Ahi + aoff0 + kl_, &As[buf][0][dst0]);                \
    gld16(Ahi + aoff1 + kl_, &As[buf][0][dst1]);                \
    gld16(Alo + aoff0 + kl_, &As[buf][1][dst0]);                \
    gld16(Alo + aoff1 + kl_, &As[buf][1][dst1]);                \
  } while (0)
#define STAGE_B(buf, kk) do {                                   \
    int kl_ = (kk)*32;                                          \
    gld16(Bhi + boff0 + kl_, &Bs[buf][0][dst0]);                \
    gld16(Bhi + boff1 + kl_, &Bs[buf][0][dst1]);                \
    gld16(Blo + boff0 + kl_, &Bs[buf][1][dst0]);                \
    gld16(Blo + boff1 + kl_, &Bs[buf][1][dst1]);                \
  } while (0)

  const int fl = lane & 15, fg = lane >> 4;
  const int pks = (((fg + (fl >> 1)) & 3) << 3);
  const int wm = wv >> 2, wn = wv & 3;   // 2M x 4N wave grid
  const int arow = wm * 128;
  const int bcol = wn * 64;

  f32x4 acc[8][4];
#pragma unroll
  for (int m = 0; m < 8; m++)
#pragma unroll
    for (int n = 0; n < 4; n++) acc[m][n] = {0.f, 0.f, 0.f, 0.f};

  STAGE_A(0, 0);
  STAGE_B(0, 0);
  __syncthreads();

  int cur = 0;
  for (int kt = 0; kt < HDIM/BK; ++kt) {   // 32 macro-tiles
    const bool st = (kt + 1 < HDIM/BK);
    s16x8 ahf[8], bhi4[4], blo4[4];

    // phase A: issue A(t+1) | read Ahi[8]+Bhi[4]+Blo[4] | 32 MFMA hi*hi
    if (st) STAGE_A(cur^1, kt + 1);
#pragma unroll
    for (int n = 0; n < 4; n++)
      bhi4[n] = *(const s16x8*)&Bs[cur][0][(bcol + n*16 + fl)*32 + pks];
#pragma unroll
    for (int n = 0; n < 4; n++)
      blo4[n] = *(const s16x8*)&Bs[cur][1][(bcol + n*16 + fl)*32 + pks];
#pragma unroll
    for (int i = 0; i < 8; i++)
      ahf[i] = *(const s16x8*)&As[cur][0][(arow + i*16 + fl)*32 + pks];
    __builtin_amdgcn_s_setprio(1);
#pragma unroll
    for (int i = 0; i < 8; i++)
#pragma unroll
      for (int n = 0; n < 4; n++)
        acc[i][n] = __builtin_amdgcn_mfma_f32_16x16x32_bf16(ahf[i], bhi4[n], acc[i][n], 0,0,0);
    __builtin_amdgcn_s_setprio(0);

    // phase B: issue B(t+1) | 32 MFMA hi*lo (regs live, no reads)
    if (st) STAGE_B(cur^1, kt + 1);
    __builtin_amdgcn_s_setprio(1);
#pragma unroll
    for (int i = 0; i < 8; i++)
#pragma unroll
      for (int n = 0; n < 4; n++)
        acc[i][n] = __builtin_amdgcn_mfma_f32_16x16x32_bf16(ahf[i], blo4[n], acc[i][n], 0,0,0);
    __builtin_amdgcn_s_setprio(0);

    // phase C: read Alo[8] (reuse ahf regs) | 32 MFMA lo*hi
#pragma unroll
    for (int i = 0; i < 8; i++)
      ahf[i] = *(const s16x8*)&As[cur][1][(arow + i*16 + fl)*32 + pks];
    __builtin_amdgcn_s_setprio(1);
#pragma unroll
    for (int i = 0; i < 8; i++)
#pragma unroll
      for (int n = 0; n < 4; n++)
        acc[i][n] = __builtin_amdgcn_mfma_f32_16x16x32_bf16(ahf[i], bhi4[n], acc[i][n], 0,0,0);
    __builtin_amdgcn_s_setprio(0);

    __syncthreads();   // drains vmcnt: t+1 landed; everyone done with cur
    cur ^= 1;
  }
#undef STAGE_A
#undef STAGE_B

  // epilogue: C/D map col=lane&15, row=(lane>>4)*4+r  [m89/m91-verified]
#pragma unroll
  for (int m = 0; m < 8; m++)
#pragma unroll
    for (int r = 0; r < 4; r++) {
      int lrow = arow + m*16 + fg*4 + r;
      if (m0 + lrow < cnt) {
        float wt = swt[lrow];
        long ob = (long)stok[lrow]*IDIM + n0 + bcol + fl;
#pragma unroll
        for (int n = 0; n < 4; n++)
          atomicAdd(&out[ob + n*16], wt * acc[m][n][r]);
      }
    }
}

// ===== K6: fused SwiGLU + down-router; writes h as bf16 (RNE) =============
// Router logits use EXACT f32 h (pre-rounding) -> routing identical to before.
// bf16(h) == what the old down kernel converted in-kernel -> y bit-identical.
__global__ __launch_bounds__(256) void swiglu_router_bf(
    const float* __restrict__ g, const float* __restrict__ u,
    unsigned short* __restrict__ hb,
    const float* __restrict__ RW,
    int* __restrict__ topi, float* __restrict__ topw) {
  int lane = threadIdx.x & 63;
  int t = blockIdx.x*4 + (threadIdx.x>>6);
  const f32x4* gr = (const f32x4*)(g + (long)t*IDIM);
  const f32x4* ur = (const f32x4*)(u + (long)t*IDIM);
  u16x4*       hr = (u16x4*)(hb + (long)t*IDIM);
  float acc[NEXP];
#pragma unroll
  for (int e = 0; e < NEXP; e++) acc[e] = 0.f;
#pragma unroll
  for (int it = 0; it < IDIM/4/64; it++) {   // 14
    int c4 = it*64 + lane;
    f32x4 gv = gr[c4], uv = ur[c4], hv;
    u16x4 hh;
#pragma unroll
    for (int j = 0; j < 4; j++) {
      float x = gv[j];
      hv[j] = x * uv[j] / (1.f + expf(-x));
      hh[j] = f2bf_rne(hv[j]);
    }
    hr[c4] = hh;
#pragma unroll
    for (int j = 0; j < 4; j++) {
      const float* wr = RW + (long)(c4*4+j)*NEXP;
#pragma unroll
      for (int e = 0; e < NEXP; e++) acc[e] += hv[j]*wr[e];
    }
  }
#pragma unroll
  for (int e = 0; e < NEXP; e++) {
    float v = acc[e];
#pragma unroll
    for (int o = 1; o < 64; o <<= 1) v += __shfl_xor(v, o);
    acc[e] = v;
  }
  if (lane == 0) top2_write(acc, t, topi, topw);
}

// ===== K7: down GEMM, both operands bf16 gld16-staged, dbuf + swizzle =====
__global__ __launch_bounds__(256) void moe_gemm_down_bf(
    const unsigned short* __restrict__ Hb, const unsigned short* __restrict__ Bw,
    const int* __restrict__ offs, const int* __restrict__ ptok,
    const float* __restrict__ pw, float* __restrict__ out)
{
  const int K = IDIM, N = HDIM;
  const int e = blockIdx.z;
  const int beg = offs[e];
  const int cnt = offs[e+1] - beg;
  const int m0 = blockIdx.y * 128;   // NO swizzle
  if (m0 >= cnt) return;
  const int n0 = blockIdx.x * 128;

  __shared__ unsigned short As[2][128*32], Bs[2][128*32];  // 32KB dbuf
  __shared__ int   stok[128];
  __shared__ float swt[128];

  const int tid = threadIdx.x, lane = tid & 63, wv = tid >> 6;  // 4 waves
  if (tid < 128) {
    int i = m0 + tid;
    stok[tid] = ptok[beg + (i < cnt ? i : 0)];
    swt[tid]  = (i < cnt) ? pw[beg + i] : 0.f;
  }
  __syncthreads();

  const int srow = lane >> 2;
  const int lc   = ((lane & 3) - ((lane >> 3) & 3)) & 3;  // pre-swizzled src
  const long aoff0 = (long)stok[wv*32 +      srow]*K + lc*8;
  const long aoff1 = (long)stok[wv*32 + 16 + srow]*K + lc*8;
  const long boff0 = ((long)e*N + n0 + wv*32 +      srow)*K + lc*8;
  const long boff1 = ((long)e*N + n0 + wv*32 + 16 + srow)*K + lc*8;
  const int dst0 = (wv*32     )*32;
  const int dst1 = (wv*32 + 16)*32;

#define STAGE(buf, kt) do {                                 \
    int kl_ = (kt)*32;                                      \
    gld16(Hb + aoff0 + kl_, &As[buf][dst0]);                \
    gld16(Hb + aoff1 + kl_, &As[buf][dst1]);                \
    gld16(Bw + boff0 + kl_, &Bs[buf][dst0]);                \
    gld16(Bw + boff1 + kl_, &Bs[buf][dst1]);                \
  } while (0)

  const int fl = lane & 15, fg = lane >> 4;
  const int pks = (((fg + (fl >> 1)) & 3) << 3);
  const int arow = (wv >> 1)*64, bcol = (wv & 1)*64;   // 2x2 wave grid

  f32x4 acc[4][4];
#pragma unroll
  for (int m = 0; m < 4; m++)
#pragma unroll
    for (int n = 0; n < 4; n++) acc[m][n] = {0.f, 0.f, 0.f, 0.f};

  STAGE(0, 0);
  __syncthreads();

  int cur = 0;
  for (int kt = 0; kt < K/BK; ++kt) {   // 112
    if (kt + 1 < K/BK) STAGE(cur^1, kt + 1);

    s16x8 ahf[4], bhf[4];
#pragma unroll
    for (int i = 0; i < 4; i++) {
      ahf[i] = *(const s16x8*)&As[cur][(arow + i*16 + fl)*32 + pks];
      bhf[i] = *(const s16x8*)&Bs[cur][(bcol + i*16 + fl)*32 + pks];
    }
    __builtin_amdgcn_s_setprio(1);
#pragma unroll
    for (int i = 0; i < 4; i++)
#pragma unroll
      for (int n = 0; n < 4; n++)
        acc[i][n] = __builtin_amdgcn_mfma_f32_16x16x32_bf16(ahf[i], bhf[n], acc[i][n], 0,0,0);
    __builtin_amdgcn_s_setprio(0);

    __syncthreads();
    cur ^= 1;
  }
#undef STAGE

#pragma unroll
  for (int m = 0; m < 4; m++)
#pragma unroll
    for (int r = 0; r < 4; r++) {
      int lrow = arow + m*16 + fg*4 + r;
      if (m0 + lrow < cnt) {
        float wt = swt[lrow];
        long ob = (long)stok[lrow]*N + n0 + bcol + fl;
#pragma unroll
        for (int n = 0; n < 4; n++)
          atomicAdd(&out[ob + n*16], wt * acc[m][n][r]);
      }
    }
}

// ========================== host launcher =================================
// Workspace aliasing (448 MiB avail, peak ~387 MB):
//   ubuf  aliases [wg_hi, wg_lo] — first written AFTER gate GEMM (last wg reader)
//   wd_hi aliases wu_hi; hbuf (bf16 h) aliases wu_lo — both dead after up GEMM
extern "C" void kernel_launch(void* const* d_in, const int* in_sizes, int n_in,
                              void* d_out, int out_size, void* d_ws, size_t ws_size,
                              hipStream_t stream)
{
  (void)in_sizes; (void)n_in;
  const float* x   = (const float*)d_in[0];
  const float* grt = (const float*)d_in[1];
  const float* gex = (const float*)d_in[2];
  const float* urt = (const float*)d_in[3];
  const float* uex = (const float*)d_in[4];
  const float* drt = (const float*)d_in[5];
  const float* dex = (const float*)d_in[6];
  float* out = (float*)d_out;

  char* base = (char*)d_ws;
  size_t off = 0;
  auto alloc = [&](size_t b) -> void* {
    void* r = base + off;
    off = (off + b + 255) & ~(size_t)255;
    return r;
  };
  const size_t szXH = (size_t)T_TOK*HDIM*2;
  const size_t szW  = (size_t)NEXP*HDIM*IDIM*2;
  const size_t szGI = (size_t)T_TOK*IDIM*4;

  unsigned short* xhi   = (unsigned short*)alloc(szXH);
  unsigned short* xlo   = (unsigned short*)alloc(szXH);
  unsigned short* wg_hi = (unsigned short*)alloc(szW);   // later: ubuf (f32)
  unsigned short* wg_lo = (unsigned short*)alloc(szW);
  unsigned short* wu_hi = (unsigned short*)alloc(szW);   // later: wd_hi
  unsigned short* wu_lo = (unsigned short*)alloc(szW);   // later: hbuf (bf16)
  float* gbuf = (float*)alloc(szGI);
  int*   topi_g = (int*)alloc(NPAIR*4);  float* topw_g = (float*)alloc(NPAIR*4);
  int*   topi_u = (int*)alloc(NPAIR*4);  float* topw_u = (float*)alloc(NPAIR*4);
  int*   topi_d = (int*)alloc(NPAIR*4);  float* topw_d = (float*)alloc(NPAIR*4);
  int* offs_g = (int*)alloc(64);
  int* offs_u = (int*)alloc(64);
  int* offs_d = (int*)alloc(64);
  int*   ptok_g = (int*)alloc(NPAIR*4);  float* pw_g = (float*)alloc(NPAIR*4);
  int*   ptok_u = (int*)alloc(NPAIR*4);  float* pw_u = (float*)alloc(NPAIR*4);
  int*   ptok_d = (int*)alloc(NPAIR*4);  float* pw_d = (float*)alloc(NPAIR*4);

  float*          ubuf  = (float*)wg_hi;
  unsigned short* wd_hi = wu_hi;
  unsigned short* hbuf  = wu_lo;

  if (off > ws_size) {
    fprintf(stderr, "[moe] ws too small: need %zu bytes, have %zu\n", off, ws_size);
    hipMemsetAsync(d_out, 0, (size_t)out_size*sizeof(float), stream);
    return;
  }

  hipMemsetAsync(gbuf, 0, szGI, stream);
  hipMemsetAsync(d_out, 0, (size_t)out_size*sizeof(float), stream);

  split_router<<<T_TOK/4, 256, 0, stream>>>(x, grt, urt, xhi, xlo,
                                            topi_g, topw_g, topi_u, topw_u);
  transpose_split_v<<<dim3(IDIM/32, HDIM/32, NEXP), dim3(8,32), 0, stream>>>(gex, wg_hi, wg_lo, HDIM, IDIM);
  transpose_split_v<<<dim3(IDIM/32, HDIM/32, NEXP), dim3(8,32), 0, stream>>>(uex, wu_hi, wu_lo, HDIM, IDIM);
  build_perm<<<NEXP, 256, 0, stream>>>(topi_g, topw_g, offs_g, ptok_g, pw_g);
  build_perm<<<NEXP, 256, 0, stream>>>(topi_u, topw_u, offs_u, ptok_u, pw_u);

  // gate GEMM (last reader of wg region): 256^2 tile; y=32 covers cnt<=8192
  moe_gemm3_mt<<<dim3(IDIM/256, 32, NEXP), 512, 0, stream>>>(
      xhi, xlo, wg_hi, wg_lo, offs_g, ptok_g, pw_g, gbuf);

  // wg region dead -> ubuf
  hipMemsetAsync(ubuf, 0, szGI, stream);
  moe_gemm3_mt<<<dim3(IDIM/256, 32, NEXP), 512, 0, stream>>>(
      xhi, xlo, wu_hi, wu_lo, offs_u, ptok_u, pw_u, ubuf);

  // wu region dead -> wd_hi (hi half) + hbuf (lo half)
  transpose_split_v<<<dim3(HDIM/32, IDIM/32, NEXP), dim3(8,32), 0, stream>>>(dex, wd_hi, nullptr, IDIM, HDIM);

  // fused: h = silu(g)*u -> bf16 hbuf + down-router top2 (on exact f32 h)
  swiglu_router_bf<<<T_TOK/4, 256, 0, stream>>>(gbuf, ubuf, hbuf, drt, topi_d, topw_d);
  build_perm<<<NEXP, 256, 0, stream>>>(topi_d, topw_d, offs_d, ptok_d, pw_d);

  moe_gemm_down_bf<<<dim3(HDIM/128, 64, NEXP), 256, 0, stream>>>(
      hbuf, wd_hi, offs_d, ptok_d, pw_d, out);
}

// Round 11
// 1579.615 us; speedup vs baseline: 1.1076x; 1.0260x over previous
//
#include <hip/hip_runtime.h>
#include <stdint.h>
#include <stdio.h>

#define T_TOK 8192
#define HDIM  1024
#define IDIM  3584
#define NEXP  8
#define NPAIR (T_TOK*2)
#define BK 32

typedef float          f32x4 __attribute__((ext_vector_type(4)));
typedef short          s16x8 __attribute__((ext_vector_type(8)));
typedef unsigned short u16x4 __attribute__((ext_vector_type(4)));
typedef unsigned short u16x8 __attribute__((ext_vector_type(8)));

__device__ __forceinline__ unsigned short f2bf_rne(float f) {
  unsigned u = __float_as_uint(f);
  u += 0x7FFFu + ((u >> 16) & 1u);
  return (unsigned short)(u >> 16);
}
__device__ __forceinline__ float bf2f(unsigned short h) {
  return __uint_as_float(((unsigned)h) << 16);
}

__device__ __forceinline__ void gld16(const void* gsrc, void* ldst) {
  typedef const unsigned int __attribute__((address_space(1))) GU;
  typedef unsigned int       __attribute__((address_space(3))) LU;
  __builtin_amdgcn_global_load_lds((GU*)(unsigned long long)gsrc,
                                   (LU*)(unsigned int)(unsigned long long)ldst,
                                   16, 0, 0);
}

// ---- shared top-2 helper (stable, lowest-index tie-break like lax.top_k)
__device__ __forceinline__ void top2_write(const float* acc, int t,
                                           int* __restrict__ topi,
                                           float* __restrict__ topw) {
  int i0 = 0; float l0 = acc[0];
#pragma unroll
  for (int e = 1; e < NEXP; e++) if (acc[e] > l0) { l0 = acc[e]; i0 = e; }
  int i1 = -1; float l1 = -3.4e38f;
#pragma unroll
  for (int e = 0; e < NEXP; e++) if (e != i0 && acc[e] > l1) { l1 = acc[e]; i1 = e; }
  float w0 = 1.f/(1.f + expf(l1 - l0));
  float w1 = 1.f/(1.f + expf(l0 - l1));
  topi[2*t]   = i0; topi[2*t+1] = i1;
  topw[2*t]   = w0; topw[2*t+1] = w1;
}

// ===== K1: FUSED x split (hi/lo) + gate/up routers (one pass over x) ======
__global__ __launch_bounds__(256) void split_router(
    const float* __restrict__ X,
    const float* __restrict__ RWg, const float* __restrict__ RWu,
    unsigned short* __restrict__ xhi, unsigned short* __restrict__ xlo,
    int* __restrict__ tig, float* __restrict__ twg,
    int* __restrict__ tiu, float* __restrict__ twu) {
  int lane = threadIdx.x & 63;
  int t = blockIdx.x*4 + (threadIdx.x>>6);
  const f32x4* xr = (const f32x4*)(X + (long)t*HDIM);
  u16x4* hr = (u16x4*)(xhi + (long)t*HDIM);
  u16x4* lr = (u16x4*)(xlo + (long)t*HDIM);
  float ag[NEXP], au[NEXP];
#pragma unroll
  for (int e = 0; e < NEXP; e++) { ag[e] = 0.f; au[e] = 0.f; }
#pragma unroll
  for (int it = 0; it < HDIM/4/64; it++) {   // 4
    int c4 = it*64 + lane;
    f32x4 xv = xr[c4];
    u16x4 hh, ll;
#pragma unroll
    for (int j = 0; j < 4; j++) {
      unsigned short hb = f2bf_rne(xv[j]);
      hh[j] = hb;
      ll[j] = f2bf_rne(xv[j] - bf2f(hb));
    }
    hr[c4] = hh; lr[c4] = ll;
#pragma unroll
    for (int j = 0; j < 4; j++) {
      const float* wg = RWg + (long)(c4*4+j)*NEXP;
      const float* wu = RWu + (long)(c4*4+j)*NEXP;
#pragma unroll
      for (int e = 0; e < NEXP; e++) { ag[e] += xv[j]*wg[e]; au[e] += xv[j]*wu[e]; }
    }
  }
#pragma unroll
  for (int e = 0; e < NEXP; e++) {
    float vg = ag[e], vu = au[e];
#pragma unroll
    for (int o = 1; o < 64; o <<= 1) { vg += __shfl_xor(vg, o); vu += __shfl_xor(vu, o); }
    ag[e] = vg; au[e] = vu;
  }
  if (lane == 0) { top2_write(ag, t, tig, twg); top2_write(au, t, tiu, twu); }
}

// ===== K2: vectorized transpose; DUAL variant covers gate+up in one go ====
__global__ void transpose_split2(const float* __restrict__ W0,
                                 unsigned short* __restrict__ hi0,
                                 unsigned short* __restrict__ lo0,
                                 const float* __restrict__ W1,
                                 unsigned short* __restrict__ hi1,
                                 unsigned short* __restrict__ lo1,
                                 int K, int N) {
  __shared__ float t[32][33];
  int z = blockIdx.z;
  const float* W = (z < NEXP) ? W0 : W1;
  unsigned short* hi = (z < NEXP) ? hi0 : hi1;
  unsigned short* lo = (z < NEXP) ? lo0 : lo1;
  long base = (long)(z & 7) * K * N;
  int n0 = blockIdx.x*32, k0 = blockIdx.y*32;
  int id = threadIdx.y*8 + threadIdx.x;
  int lrr = id >> 3, lcq = id & 7;
  f32x4 v = *(const f32x4*)&W[base + (long)(k0+lrr)*N + n0 + lcq*4];
  t[lrr][lcq*4+0] = v[0]; t[lrr][lcq*4+1] = v[1];
  t[lrr][lcq*4+2] = v[2]; t[lrr][lcq*4+3] = v[3];
  __syncthreads();
  int n = threadIdx.y, kq = threadIdx.x;
  u16x4 h, l;
#pragma unroll
  for (int r = 0; r < 4; r++) {
    float f = t[kq*4+r][n];
    unsigned short hb = f2bf_rne(f);
    h[r] = hb;
    l[r] = f2bf_rne(f - bf2f(hb));
  }
  long o = base + (long)(n0+n)*K + k0 + kq*4;
  *(u16x4*)&hi[o] = h;
  if (lo) *(u16x4*)&lo[o] = l;
}

__global__ void transpose_split_v(const float* __restrict__ W,
                                  unsigned short* __restrict__ hi,
                                  unsigned short* __restrict__ lo,
                                  int K, int N) {
  __shared__ float t[32][33];
  long base = (long)blockIdx.z * K * N;
  int n0 = blockIdx.x*32, k0 = blockIdx.y*32;
  int id = threadIdx.y*8 + threadIdx.x;
  int lrr = id >> 3, lcq = id & 7;
  f32x4 v = *(const f32x4*)&W[base + (long)(k0+lrr)*N + n0 + lcq*4];
  t[lrr][lcq*4+0] = v[0]; t[lrr][lcq*4+1] = v[1];
  t[lrr][lcq*4+2] = v[2]; t[lrr][lcq*4+3] = v[3];
  __syncthreads();
  int n = threadIdx.y, kq = threadIdx.x;
  u16x4 h, l;
#pragma unroll
  for (int r = 0; r < 4; r++) {
    float f = t[kq*4+r][n];
    unsigned short hb = f2bf_rne(f);
    h[r] = hb;
    l[r] = f2bf_rne(f - bf2f(hb));
  }
  long o = base + (long)(n0+n)*K + k0 + kq*4;
  *(u16x4*)&hi[o] = h;
  if (lo) *(u16x4*)&lo[o] = l;
}

// ===== K4: deterministic stable per-expert compaction ====================
__device__ __forceinline__ void perm_body(const int* __restrict__ topi,
                                          const float* __restrict__ topw,
                                          int* __restrict__ offs,
                                          int* __restrict__ ptok,
                                          float* __restrict__ pw, int e) {
  int tid = threadIdx.x, lane = tid & 63, wv = tid >> 6;
  __shared__ int cnt[NEXP];
  __shared__ int wsum[4];
  if (tid < NEXP) cnt[tid] = 0;
  __syncthreads();
  for (int p = tid; p < NPAIR; p += 256) atomicAdd(&cnt[topi[p]], 1);
  __syncthreads();
  int base = 0;
#pragma unroll
  for (int e2 = 0; e2 < NEXP; e2++) if (e2 < e) base += cnt[e2];
  if (tid == 0) { offs[e] = base; if (e == NEXP-1) offs[NEXP] = base + cnt[e]; }
  for (int p0 = 0; p0 < NPAIR; p0 += 256) {
    int p = p0 + tid;
    bool m = (topi[p] == e);
    unsigned long long b = __ballot(m);
    int lp = __popcll(b & ((1ull << lane) - 1ull));
    if (lane == 0) wsum[wv] = __popcll(b);
    __syncthreads();
    int woff = 0;
#pragma unroll
    for (int w2 = 0; w2 < 4; w2++) if (w2 < wv) woff += wsum[w2];
    int tot = wsum[0] + wsum[1] + wsum[2] + wsum[3];
    if (m) { int dst = base + woff + lp; ptok[dst] = p >> 1; pw[dst] = topw[p]; }
    base += tot;
    __syncthreads();
  }
}
__global__ __launch_bounds__(256) void build_perm(const int* topi, const float* topw,
                                                  int* offs, int* ptok, float* pw) {
  perm_body(topi, topw, offs, ptok, pw, blockIdx.x);
}
__global__ __launch_bounds__(256) void build_perm2(
    const int* tig, const float* twg, int* offsg, int* ptokg, float* pwg,
    const int* tiu, const float* twu, int* offsu, int* ptoku, float* pwu) {
  if (blockIdx.x < NEXP) perm_body(tig, twg, offsg, ptokg, pwg, blockIdx.x);
  else                   perm_body(tiu, twu, offsu, ptoku, pwu, blockIdx.x - NEXP);
}

// ===== K5: gathered 3-term GEMM, 256x256 macro-tile, 6-PHASE LOCKSTEP =====
// m201-template port: per phase {fresh ds_reads + 1 plane-stage | s_barrier |
// sched_barrier | setprio(1) 16xMFMA setprio(0) | s_barrier}. Raw barriers
// (no counter drain) keep 8 waves phase-locked; single vmcnt(0) at P6 (the
// 8 stage-loads issued P1-P4 have ~3k cyc to land). Memory pattern = round-8
// proven (4 planes/K-tile, dbuf, FETCH 474MB, 0 conflicts). Per-acc term
// order hihi->hilo->lohi preserved -> bit-identical output.
__global__ __launch_bounds__(512, 2) void moe_gemm3_8p(
    const unsigned short* __restrict__ Ahi, const unsigned short* __restrict__ Alo,
    const unsigned short* __restrict__ Bhi, const unsigned short* __restrict__ Blo,
    const int* __restrict__ offs, const int* __restrict__ ptok,
    const float* __restrict__ pw, float* __restrict__ out)
{
  const int e = blockIdx.z;
  const int beg = offs[e];
  const int cnt = offs[e+1] - beg;
  const int m0 = blockIdx.y * 256;   // NO XCD swizzle (round-3 lesson)
  if (m0 >= cnt) return;
  const int n0 = blockIdx.x * 256;

  __shared__ unsigned short As[2][2][256*32];  // [buf][hi/lo]  64KB
  __shared__ unsigned short Bs[2][2][256*32];  // 64KB
  __shared__ int   stok[256];
  __shared__ float swt[256];

  const int tid = threadIdx.x, lane = tid & 63, wv = tid >> 6;
  if (tid < 256) {
    int i = m0 + tid;
    stok[tid] = ptok[beg + (i < cnt ? i : 0)];
    swt[tid]  = (i < cnt) ? pw[beg + i] : 0.f;
  }
  __syncthreads();

  const int srow = lane >> 2;
  const int lc   = ((lane & 3) - ((lane >> 3) & 3)) & 3;  // pre-swizzled src
  const long aoff0 = (long)stok[wv*32 +      srow]*HDIM + lc*8;
  const long aoff1 = (long)stok[wv*32 + 16 + srow]*HDIM + lc*8;
  const long boff0 = ((long)e*IDIM + n0 + wv*32 +      srow)*HDIM + lc*8;
  const long boff1 = ((long)e*IDIM + n0 + wv*32 + 16 + srow)*HDIM + lc*8;
  const int dst0 = (wv*32     )*32;
  const int dst1 = (wv*32 + 16)*32;

#define STAGE_AH(buf, kk) do { int kl_ = (kk)*32;                 \
    gld16(Ahi + aoff0 + kl_, &As[buf][0][dst0]);                  \
    gld16(Ahi + aoff1 + kl_, &As[buf][0][dst1]); } while (0)
#define STAGE_AL(buf, kk) do { int kl_ = (kk)*32;                 \
    gld16(Alo + aoff0 + kl_, &As[buf][1][dst0]);                  \
    gld16(Alo + aoff1 + kl_, &As[buf][1][dst1]); } while (0)
#define STAGE_BH(buf, kk) do { int kl_ = (kk)*32;                 \
    gld16(Bhi + boff0 + kl_, &Bs[buf][0][dst0]);                  \
    gld16(Bhi + boff1 + kl_, &Bs[buf][0][dst1]); } while (0)
#define STAGE_BL(buf, kk) do { int kl_ = (kk)*32;                 \
    gld16(Blo + boff0 + kl_, &Bs[buf][1][dst0]);                  \
    gld16(Blo + boff1 + kl_, &Bs[buf][1][dst1]); } while (0)

  const int fl = lane & 15, fg = lane >> 4;
  const int pks = (((fg + (fl >> 1)) & 3) << 3);
  const int wm = wv >> 2, wn = wv & 3;   // 2M x 4N wave grid
  const int arow = wm * 128;
  const int bcol = wn * 64;

  f32x4 acc[8][4];
#pragma unroll
  for (int m = 0; m < 8; m++)
#pragma unroll
    for (int n = 0; n < 4; n++) acc[m][n] = {0.f, 0.f, 0.f, 0.f};

  STAGE_AH(0, 0); STAGE_AL(0, 0); STAGE_BH(0, 0); STAGE_BL(0, 0);
  __syncthreads();   // full drain: tile 0 landed

  int cur = 0;
  for (int kt = 0; kt < HDIM/BK; ++kt) {   // 32 K-tiles
    const bool st = (kt + 1 < HDIM/BK);
    s16x8 ahi[8], bhi[4], blo[4], alo[4];

    // ---- P1: read Ahi[0:4] + Bhi[0:4] | stage Ahi(t+1) | 16 MFMA hi*hi lo-half
#pragma unroll
    for (int i = 0; i < 4; i++)
      ahi[i] = *(const s16x8*)&As[cur][0][(arow + i*16 + fl)*32 + pks];
#pragma unroll
    for (int n = 0; n < 4; n++)
      bhi[n] = *(const s16x8*)&Bs[cur][0][(bcol + n*16 + fl)*32 + pks];
    if (st) STAGE_AH(cur^1, kt + 1);
    __builtin_amdgcn_s_barrier();
    __builtin_amdgcn_sched_barrier(0);
    __builtin_amdgcn_s_setprio(1);
#pragma unroll
    for (int i = 0; i < 4; i++)
#pragma unroll
      for (int n = 0; n < 4; n++)
        acc[i][n] = __builtin_amdgcn_mfma_f32_16x16x32_bf16(ahi[i], bhi[n], acc[i][n], 0,0,0);
    __builtin_amdgcn_s_setprio(0);
    __builtin_amdgcn_s_barrier();

    // ---- P2: read Ahi[4:8] | stage Alo(t+1) | 16 MFMA hi*hi hi-half
#pragma unroll
    for (int i = 0; i < 4; i++)
      ahi[4+i] = *(const s16x8*)&As[cur][0][(arow + (4+i)*16 + fl)*32 + pks];
    if (st) STAGE_AL(cur^1, kt + 1);
    __builtin_amdgcn_s_barrier();
    __builtin_amdgcn_sched_barrier(0);
    __builtin_amdgcn_s_setprio(1);
#pragma unroll
    for (int i = 0; i < 4; i++)
#pragma unroll
      for (int n = 0; n < 4; n++)
        acc[4+i][n] = __builtin_amdgcn_mfma_f32_16x16x32_bf16(ahi[4+i], bhi[n], acc[4+i][n], 0,0,0);
    __builtin_amdgcn_s_setprio(0);
    __builtin_amdgcn_s_barrier();

    // ---- P3: read Blo[0:4] | stage Bhi(t+1) | 16 MFMA hi*lo lo-half
#pragma unroll
    for (int n = 0; n < 4; n++)
      blo[n] = *(const s16x8*)&Bs[cur][1][(bcol + n*16 + fl)*32 + pks];
    if (st) STAGE_BH(cur^1, kt + 1);
    __builtin_amdgcn_s_barrier();
    __builtin_amdgcn_sched_barrier(0);
    __builtin_amdgcn_s_setprio(1);
#pragma unroll
    for (int i = 0; i < 4; i++)
#pragma unroll
      for (int n = 0; n < 4; n++)
        acc[i][n] = __builtin_amdgcn_mfma_f32_16x16x32_bf16(ahi[i], blo[n], acc[i][n], 0,0,0);
    __builtin_amdgcn_s_setprio(0);
    __builtin_amdgcn_s_barrier();

    // ---- P4: read Alo[0:4] | stage Blo(t+1) | 16 MFMA hi*lo hi-half
#pragma unroll
    for (int i = 0; i < 4; i++)
      alo[i] = *(const s16x8*)&As[cur][1][(arow + i*16 + fl)*32 + pks];
    if (st) STAGE_BL(cur^1, kt + 1);
    __builtin_amdgcn_s_barrier();
    __builtin_amdgcn_sched_barrier(0);
    __builtin_amdgcn_s_setprio(1);
#pragma unroll
    for (int i = 0; i < 4; i++)
#pragma unroll
      for (int n = 0; n < 4; n++)
        acc[4+i][n] = __builtin_amdgcn_mfma_f32_16x16x32_bf16(ahi[4+i], blo[n], acc[4+i][n], 0,0,0);
    __builtin_amdgcn_s_setprio(0);
    __builtin_amdgcn_s_barrier();

    // ---- P5: read Alo[4:8] (into ahi[0:4], dead) | 16 MFMA lo*hi lo-half
#pragma unroll
    for (int i = 0; i < 4; i++)
      ahi[i] = *(const s16x8*)&As[cur][1][(arow + (4+i)*16 + fl)*32 + pks];
    __builtin_amdgcn_s_barrier();
    __builtin_amdgcn_sched_barrier(0);
    __builtin_amdgcn_s_setprio(1);
#pragma unroll
    for (int i = 0; i < 4; i++)
#pragma unroll
      for (int n = 0; n < 4; n++)
        acc[i][n] = __builtin_amdgcn_mfma_f32_16x16x32_bf16(alo[i], bhi[n], acc[i][n], 0,0,0);
    __builtin_amdgcn_s_setprio(0);
    __builtin_amdgcn_s_barrier();

    // ---- P6: no reads | 16 MFMA lo*hi hi-half | vmcnt(0) + tile barrier
    __builtin_amdgcn_sched_barrier(0);
    __builtin_amdgcn_s_setprio(1);
#pragma unroll
    for (int i = 0; i < 4; i++)
#pragma unroll
      for (int n = 0; n < 4; n++)
        acc[4+i][n] = __builtin_amdgcn_mfma_f32_16x16x32_bf16(ahi[i], bhi[n], acc[4+i][n], 0,0,0);
    __builtin_amdgcn_s_setprio(0);
    asm volatile("s_waitcnt vmcnt(0)" ::: "memory");
    __builtin_amdgcn_s_barrier();

    cur ^= 1;
  }
#undef STAGE_AH
#undef STAGE_AL
#undef STAGE_BH
#undef STAGE_BL

  // epilogue: C/D map col=lane&15, row=(lane>>4)*4+r  [m89/m91-verified]
#pragma unroll
  for (int m = 0; m < 8; m++)
#pragma unroll
    for (int r = 0; r < 4; r++) {
      int lrow = arow + m*16 + fg*4 + r;
      if (m0 + lrow < cnt) {
        float wt = swt[lrow];
        long ob = (long)stok[lrow]*IDIM + n0 + bcol + fl;
#pragma unroll
        for (int n = 0; n < 4; n++)
          atomicAdd(&out[ob + n*16], wt * acc[m][n][r]);
      }
    }
}

// ===== K6: fused SwiGLU + down-router; writes h as bf16 (RNE) =============
__global__ __launch_bounds__(256) void swiglu_router_bf(
    const float* __restrict__ g, const float* __restrict__ u,
    unsigned short* __restrict__ hb,
    const float* __restrict__ RW,
    int* __restrict__ topi, float* __restrict__ topw) {
  int lane = threadIdx.x & 63;
  int t = blockIdx.x*4 + (threadIdx.x>>6);
  const f32x4* gr = (const f32x4*)(g + (long)t*IDIM);
  const f32x4* ur = (const f32x4*)(u + (long)t*IDIM);
  u16x4*       hr = (u16x4*)(hb + (long)t*IDIM);
  float acc[NEXP];
#pragma unroll
  for (int e = 0; e < NEXP; e++) acc[e] = 0.f;
#pragma unroll
  for (int it = 0; it < IDIM/4/64; it++) {   // 14
    int c4 = it*64 + lane;
    f32x4 gv = gr[c4], uv = ur[c4], hv;
    u16x4 hh;
#pragma unroll
    for (int j = 0; j < 4; j++) {
      float x = gv[j];
      hv[j] = x * uv[j] / (1.f + expf(-x));
      hh[j] = f2bf_rne(hv[j]);
    }
    hr[c4] = hh;
#pragma unroll
    for (int j = 0; j < 4; j++) {
      const float* wr = RW + (long)(c4*4+j)*NEXP;
#pragma unroll
      for (int e = 0; e < NEXP; e++) acc[e] += hv[j]*wr[e];
    }
  }
#pragma unroll
  for (int e = 0; e < NEXP; e++) {
    float v = acc[e];
#pragma unroll
    for (int o = 1; o < 64; o <<= 1) v += __shfl_xor(v, o);
    acc[e] = v;
  }
  if (lane == 0) top2_write(acc, t, topi, topw);
}

// ===== K7: down GEMM, both operands bf16 gld16-staged, dbuf + swizzle =====
__global__ __launch_bounds__(256) void moe_gemm_down_bf(
    const unsigned short* __restrict__ Hb, const unsigned short* __restrict__ Bw,
    const int* __restrict__ offs, const int* __restrict__ ptok,
    const float* __restrict__ pw, float* __restrict__ out)
{
  const int K = IDIM, N = HDIM;
  const int e = blockIdx.z;
  const int beg = offs[e];
  const int cnt = offs[e+1] - beg;
  const int m0 = blockIdx.y * 128;   // NO swizzle
  if (m0 >= cnt) return;
  const int n0 = blockIdx.x * 128;

  __shared__ unsigned short As[2][128*32], Bs[2][128*32];  // 32KB dbuf
  __shared__ int   stok[128];
  __shared__ float swt[128];

  const int tid = threadIdx.x, lane = tid & 63, wv = tid >> 6;  // 4 waves
  if (tid < 128) {
    int i = m0 + tid;
    stok[tid] = ptok[beg + (i < cnt ? i : 0)];
    swt[tid]  = (i < cnt) ? pw[beg + i] : 0.f;
  }
  __syncthreads();

  const int srow = lane >> 2;
  const int lc   = ((lane & 3) - ((lane >> 3) & 3)) & 3;
  const long aoff0 = (long)stok[wv*32 +      srow]*K + lc*8;
  const long aoff1 = (long)stok[wv*32 + 16 + srow]*K + lc*8;
  const long boff0 = ((long)e*N + n0 + wv*32 +      srow)*K + lc*8;
  const long boff1 = ((long)e*N + n0 + wv*32 + 16 + srow)*K + lc*8;
  const int dst0 = (wv*32     )*32;
  const int dst1 = (wv*32 + 16)*32;

#define STAGE(buf, kt) do {                                 \
    int kl_ = (kt)*32;                                      \
    gld16(Hb + aoff0 + kl_, &As[buf][dst0]);                \
    gld16(Hb + aoff1 + kl_, &As[buf][dst1]);                \
    gld16(Bw + boff0 + kl_, &Bs[buf][dst0]);                \
    gld16(Bw + boff1 + kl_, &Bs[buf][dst1]);                \
  } while (0)

  const int fl = lane & 15, fg = lane >> 4;
  const int pks = (((fg + (fl >> 1)) & 3) << 3);
  const int arow = (wv >> 1)*64, bcol = (wv & 1)*64;

  f32x4 acc[4][4];
#pragma unroll
  for (int m = 0; m < 4; m++)
#pragma unroll
    for (int n = 0; n < 4; n++) acc[m][n] = {0.f, 0.f, 0.f, 0.f};

  STAGE(0, 0);
  __syncthreads();

  int cur = 0;
  for (int kt = 0; kt < K/BK; ++kt) {   // 112
    if (kt + 1 < K/BK) STAGE(cur^1, kt + 1);

    s16x8 ahf[4], bhf[4];
#pragma unroll
    for (int i = 0; i < 4; i++) {
      ahf[i] = *(const s16x8*)&As[cur][(arow + i*16 + fl)*32 + pks];
      bhf[i] = *(const s16x8*)&Bs[cur][(bcol + i*16 + fl)*32 + pks];
    }
    __builtin_amdgcn_s_setprio(1);
#pragma unroll
    for (int i = 0; i < 4; i++)
#pragma unroll
      for (int n = 0; n < 4; n++)
        acc[i][n] = __builtin_amdgcn_mfma_f32_16x16x32_bf16(ahf[i], bhf[n], acc[i][n], 0,0,0);
    __builtin_amdgcn_s_setprio(0);

    __syncthreads();
    cur ^= 1;
  }
#undef STAGE

#pragma unroll
  for (int m = 0; m < 4; m++)
#pragma unroll
    for (int r = 0; r < 4; r++) {
      int lrow = arow + m*16 + fg*4 + r;
      if (m0 + lrow < cnt) {
        float wt = swt[lrow];
        long ob = (long)stok[lrow]*N + n0 + bcol + fl;
#pragma unroll
        for (int n = 0; n < 4; n++)
          atomicAdd(&out[ob + n*16], wt * acc[m][n][r]);
      }
    }
}

// ========================== host launcher =================================
// Workspace aliasing (448 MiB avail, peak ~387 MB):
//   ubuf  aliases [wg_hi, wg_lo] — first written AFTER gate GEMM (last wg reader)
//   wd_hi aliases wu_hi; hbuf (bf16 h) aliases wu_lo — both dead after up GEMM
extern "C" void kernel_launch(void* const* d_in, const int* in_sizes, int n_in,
                              void* d_out, int out_size, void* d_ws, size_t ws_size,
                              hipStream_t stream)
{
  (void)in_sizes; (void)n_in;
  const float* x   = (const float*)d_in[0];
  const float* grt = (const float*)d_in[1];
  const float* gex = (const float*)d_in[2];
  const float* urt = (const float*)d_in[3];
  const float* uex = (const float*)d_in[4];
  const float* drt = (const float*)d_in[5];
  const float* dex = (const float*)d_in[6];
  float* out = (float*)d_out;

  char* base = (char*)d_ws;
  size_t off = 0;
  auto alloc = [&](size_t b) -> void* {
    void* r = base + off;
    off = (off + b + 255) & ~(size_t)255;
    return r;
  };
  const size_t szXH = (size_t)T_TOK*HDIM*2;
  const size_t szW  = (size_t)NEXP*HDIM*IDIM*2;
  const size_t szGI = (size_t)T_TOK*IDIM*4;

  unsigned short* xhi   = (unsigned short*)alloc(szXH);
  unsigned short* xlo   = (unsigned short*)alloc(szXH);
  unsigned short* wg_hi = (unsigned short*)alloc(szW);   // later: ubuf (f32)
  unsigned short* wg_lo = (unsigned short*)alloc(szW);
  unsigned short* wu_hi = (unsigned short*)alloc(szW);   // later: wd_hi
  unsigned short* wu_lo = (unsigned short*)alloc(szW);   // later: hbuf (bf16)
  float* gbuf = (float*)alloc(szGI);
  int*   topi_g = (int*)alloc(NPAIR*4);  float* topw_g = (float*)alloc(NPAIR*4);
  int*   topi_u = (int*)alloc(NPAIR*4);  float* topw_u = (float*)alloc(NPAIR*4);
  int*   topi_d = (int*)alloc(NPAIR*4);  float* topw_d = (float*)alloc(NPAIR*4);
  int* offs_g = (int*)alloc(64);
  int* offs_u = (int*)alloc(64);
  int* offs_d = (int*)alloc(64);
  int*   ptok_g = (int*)alloc(NPAIR*4);  float* pw_g = (float*)alloc(NPAIR*4);
  int*   ptok_u = (int*)alloc(NPAIR*4);  float* pw_u = (float*)alloc(NPAIR*4);
  int*   ptok_d = (int*)alloc(NPAIR*4);  float* pw_d = (float*)alloc(NPAIR*4);

  float*          ubuf  = (float*)wg_hi;
  unsigned short* wd_hi = wu_hi;
  unsigned short* hbuf  = wu_lo;

  if (off > ws_size) {
    fprintf(stderr, "[moe] ws too small: need %zu bytes, have %zu\n", off, ws_size);
    hipMemsetAsync(d_out, 0, (size_t)out_size*sizeof(float), stream);
    return;
  }

  hipMemsetAsync(gbuf, 0, szGI, stream);
  hipMemsetAsync(d_out, 0, (size_t)out_size*sizeof(float), stream);

  split_router<<<T_TOK/4, 256, 0, stream>>>(x, grt, urt, xhi, xlo,
                                            topi_g, topw_g, topi_u, topw_u);
  transpose_split2<<<dim3(IDIM/32, HDIM/32, 2*NEXP), dim3(8,32), 0, stream>>>(
      gex, wg_hi, wg_lo, uex, wu_hi, wu_lo, HDIM, IDIM);
  build_perm2<<<2*NEXP, 256, 0, stream>>>(topi_g, topw_g, offs_g, ptok_g, pw_g,
                                          topi_u, topw_u, offs_u, ptok_u, pw_u);

  // gate GEMM (last reader of wg region)
  moe_gemm3_8p<<<dim3(IDIM/256, 32, NEXP), 512, 0, stream>>>(
      xhi, xlo, wg_hi, wg_lo, offs_g, ptok_g, pw_g, gbuf);

  // wg region dead -> ubuf
  hipMemsetAsync(ubuf, 0, szGI, stream);
  moe_gemm3_8p<<<dim3(IDIM/256, 32, NEXP), 512, 0, stream>>>(
      xhi, xlo, wu_hi, wu_lo, offs_u, ptok_u, pw_u, ubuf);

  // wu region dead -> wd_hi (hi) + hbuf
  transpose_split_v<<<dim3(HDIM/32, IDIM/32, NEXP), dim3(8,32), 0, stream>>>(dex, wd_hi, nullptr, IDIM, HDIM);

  // fused: h = silu(g)*u -> bf16 hbuf + down-router top2 (on exact f32 h)
  swiglu_router_bf<<<T_TOK/4, 256, 0, stream>>>(gbuf, ubuf, hbuf, drt, topi_d, topw_d);
  build_perm<<<NEXP, 256, 0, stream>>>(topi_d, topw_d, offs_d, ptok_d, pw_d);

  moe_gemm_down_bf<<<dim3(HDIM/128, 64, NEXP), 256, 0, stream>>>(
      hbuf, wd_hi, offs_d, ptok_d, pw_d, out);
}

// Round 12
// 1538.172 us; speedup vs baseline: 1.1375x; 1.0269x over previous
//
#include <hip/hip_runtime.h>
#include <stdint.h>
#include <stdio.h>

#define T_TOK 8192
#define HDIM  1024
#define IDIM  3584
#define NEXP  8
#define NPAIR (T_TOK*2)
#define BK 32

typedef float          f32x4 __attribute__((ext_vector_type(4)));
typedef short          s16x8 __attribute__((ext_vector_type(8)));
typedef unsigned short u16x4 __attribute__((ext_vector_type(4)));
typedef unsigned short u16x8 __attribute__((ext_vector_type(8)));

__device__ __forceinline__ unsigned short f2bf_rne(float f) {
  unsigned u = __float_as_uint(f);
  u += 0x7FFFu + ((u >> 16) & 1u);
  return (unsigned short)(u >> 16);
}
__device__ __forceinline__ float bf2f(unsigned short h) {
  return __uint_as_float(((unsigned)h) << 16);
}

__device__ __forceinline__ void gld16(const void* gsrc, void* ldst) {
  typedef const unsigned int __attribute__((address_space(1))) GU;
  typedef unsigned int       __attribute__((address_space(3))) LU;
  __builtin_amdgcn_global_load_lds((GU*)(unsigned long long)gsrc,
                                   (LU*)(unsigned int)(unsigned long long)ldst,
                                   16, 0, 0);
}

// ---- shared top-2 helper (stable, lowest-index tie-break like lax.top_k)
__device__ __forceinline__ void top2_write(const float* acc, int t,
                                           int* __restrict__ topi,
                                           float* __restrict__ topw) {
  int i0 = 0; float l0 = acc[0];
#pragma unroll
  for (int e = 1; e < NEXP; e++) if (acc[e] > l0) { l0 = acc[e]; i0 = e; }
  int i1 = -1; float l1 = -3.4e38f;
#pragma unroll
  for (int e = 0; e < NEXP; e++) if (e != i0 && acc[e] > l1) { l1 = acc[e]; i1 = e; }
  float w0 = 1.f/(1.f + expf(l1 - l0));
  float w1 = 1.f/(1.f + expf(l0 - l1));
  topi[2*t]   = i0; topi[2*t+1] = i1;
  topw[2*t]   = w0; topw[2*t+1] = w1;
}

// ===== K1: FUSED x split (hi/lo) + gate/up routers (one pass over x) ======
__global__ __launch_bounds__(256) void split_router(
    const float* __restrict__ X,
    const float* __restrict__ RWg, const float* __restrict__ RWu,
    unsigned short* __restrict__ xhi, unsigned short* __restrict__ xlo,
    int* __restrict__ tig, float* __restrict__ twg,
    int* __restrict__ tiu, float* __restrict__ twu) {
  int lane = threadIdx.x & 63;
  int t = blockIdx.x*4 + (threadIdx.x>>6);
  const f32x4* xr = (const f32x4*)(X + (long)t*HDIM);
  u16x4* hr = (u16x4*)(xhi + (long)t*HDIM);
  u16x4* lr = (u16x4*)(xlo + (long)t*HDIM);
  float ag[NEXP], au[NEXP];
#pragma unroll
  for (int e = 0; e < NEXP; e++) { ag[e] = 0.f; au[e] = 0.f; }
#pragma unroll
  for (int it = 0; it < HDIM/4/64; it++) {   // 4
    int c4 = it*64 + lane;
    f32x4 xv = xr[c4];
    u16x4 hh, ll;
#pragma unroll
    for (int j = 0; j < 4; j++) {
      unsigned short hb = f2bf_rne(xv[j]);
      hh[j] = hb;
      ll[j] = f2bf_rne(xv[j] - bf2f(hb));
    }
    hr[c4] = hh; lr[c4] = ll;
#pragma unroll
    for (int j = 0; j < 4; j++) {
      const float* wg = RWg + (long)(c4*4+j)*NEXP;
      const float* wu = RWu + (long)(c4*4+j)*NEXP;
#pragma unroll
      for (int e = 0; e < NEXP; e++) { ag[e] += xv[j]*wg[e]; au[e] += xv[j]*wu[e]; }
    }
  }
#pragma unroll
  for (int e = 0; e < NEXP; e++) {
    float vg = ag[e], vu = au[e];
#pragma unroll
    for (int o = 1; o < 64; o <<= 1) { vg += __shfl_xor(vg, o); vu += __shfl_xor(vu, o); }
    ag[e] = vg; au[e] = vu;
  }
  if (lane == 0) { top2_write(ag, t, tig, twg); top2_write(au, t, tiu, twu); }
}

// ===== K2: ALL-IN-ONE vectorized transpose (gate, up, down in one grid) ===
// z<8: gate [H][I]; z<16: up [H][I]; z>=16: down [I][H] (block roles swapped
// so the same 112x32 grid covers both shapes).
__global__ void transpose_split3(const float* __restrict__ gex,
                                 unsigned short* __restrict__ wg_hi,
                                 unsigned short* __restrict__ wg_lo,
                                 const float* __restrict__ uex,
                                 unsigned short* __restrict__ wu_hi,
                                 unsigned short* __restrict__ wu_lo,
                                 const float* __restrict__ dex,
                                 unsigned short* __restrict__ wd_hi) {
  __shared__ float t[32][33];
  int z = blockIdx.z;
  const float* W; unsigned short *hi, *lo; int K, N, k0, n0;
  if (z < NEXP)        { W = gex; hi = wg_hi; lo = wg_lo; K = HDIM; N = IDIM;
                         n0 = blockIdx.x*32; k0 = blockIdx.y*32; }
  else if (z < 2*NEXP) { W = uex; hi = wu_hi; lo = wu_lo; K = HDIM; N = IDIM;
                         n0 = blockIdx.x*32; k0 = blockIdx.y*32; }
  else                 { W = dex; hi = wd_hi; lo = nullptr; K = IDIM; N = HDIM;
                         k0 = blockIdx.x*32; n0 = blockIdx.y*32; }
  long base = (long)(z & 7) * K * N;
  int id = threadIdx.y*8 + threadIdx.x;
  int lrr = id >> 3, lcq = id & 7;
  f32x4 v = *(const f32x4*)&W[base + (long)(k0+lrr)*N + n0 + lcq*4];
  t[lrr][lcq*4+0] = v[0]; t[lrr][lcq*4+1] = v[1];
  t[lrr][lcq*4+2] = v[2]; t[lrr][lcq*4+3] = v[3];
  __syncthreads();
  int n = threadIdx.y, kq = threadIdx.x;
  u16x4 h, l;
#pragma unroll
  for (int r = 0; r < 4; r++) {
    float f = t[kq*4+r][n];
    unsigned short hb = f2bf_rne(f);
    h[r] = hb;
    l[r] = f2bf_rne(f - bf2f(hb));
  }
  long o = base + (long)(n0+n)*K + k0 + kq*4;
  *(u16x4*)&hi[o] = h;
  if (lo) *(u16x4*)&lo[o] = l;
}

// ===== K4: deterministic stable per-expert compaction ====================
__device__ __forceinline__ void perm_body(const int* __restrict__ topi,
                                          const float* __restrict__ topw,
                                          int* __restrict__ offs,
                                          int* __restrict__ ptok,
                                          float* __restrict__ pw, int e) {
  int tid = threadIdx.x, lane = tid & 63, wv = tid >> 6;
  __shared__ int cnt[NEXP];
  __shared__ int wsum[4];
  if (tid < NEXP) cnt[tid] = 0;
  __syncthreads();
  for (int p = tid; p < NPAIR; p += 256) atomicAdd(&cnt[topi[p]], 1);
  __syncthreads();
  int base = 0;
#pragma unroll
  for (int e2 = 0; e2 < NEXP; e2++) if (e2 < e) base += cnt[e2];
  if (tid == 0) { offs[e] = base; if (e == NEXP-1) offs[NEXP] = base + cnt[e]; }
  for (int p0 = 0; p0 < NPAIR; p0 += 256) {
    int p = p0 + tid;
    bool m = (topi[p] == e);
    unsigned long long b = __ballot(m);
    int lp = __popcll(b & ((1ull << lane) - 1ull));
    if (lane == 0) wsum[wv] = __popcll(b);
    __syncthreads();
    int woff = 0;
#pragma unroll
    for (int w2 = 0; w2 < 4; w2++) if (w2 < wv) woff += wsum[w2];
    int tot = wsum[0] + wsum[1] + wsum[2] + wsum[3];
    if (m) { int dst = base + woff + lp; ptok[dst] = p >> 1; pw[dst] = topw[p]; }
    base += tot;
    __syncthreads();
  }
}
__global__ __launch_bounds__(256) void build_perm(const int* topi, const float* topw,
                                                  int* offs, int* ptok, float* pw) {
  perm_body(topi, topw, offs, ptok, pw, blockIdx.x);
}
__global__ __launch_bounds__(256) void build_perm2(
    const int* tig, const float* twg, int* offsg, int* ptokg, float* pwg,
    const int* tiu, const float* twu, int* offsu, int* ptoku, float* pwu) {
  if (blockIdx.x < NEXP) perm_body(tig, twg, offsg, ptokg, pwg, blockIdx.x);
  else                   perm_body(tiu, twu, offsu, ptoku, pwu, blockIdx.x - NEXP);
}

// ===== K5: gathered 3-term GEMM, 256x256 MACRO-TILE (measured best: 457us)
// R8/R10 structure: per K-step stage all 4 planes into dbuf (each plane
// streamed from HBM once per block; FETCH 474MB, conflicts 0), 3 phase-
// clusters of 32 MFMA (hihi -> hilo -> lohi), single __syncthreads per tile.
// Three schedule-surgery attempts (R7/R9/R11) all landed >= this: plateau.
__global__ __launch_bounds__(512) void moe_gemm3_mt(
    const unsigned short* __restrict__ Ahi, const unsigned short* __restrict__ Alo,
    const unsigned short* __restrict__ Bhi, const unsigned short* __restrict__ Blo,
    const int* __restrict__ offs, const int* __restrict__ ptok,
    const float* __restrict__ pw, float* __restrict__ out)
{
  const int e = blockIdx.z;
  const int beg = offs[e];
  const int cnt = offs[e+1] - beg;
  const int m0 = blockIdx.y * 256;   // NO XCD swizzle (round-3 lesson)
  if (m0 >= cnt) return;
  const int n0 = blockIdx.x * 256;

  __shared__ unsigned short As[2][2][256*32];  // [buf][hi/lo]  64KB
  __shared__ unsigned short Bs[2][2][256*32];  // 64KB
  __shared__ int   stok[256];
  __shared__ float swt[256];

  const int tid = threadIdx.x, lane = tid & 63, wv = tid >> 6;
  if (tid < 256) {
    int i = m0 + tid;
    stok[tid] = ptok[beg + (i < cnt ? i : 0)];
    swt[tid]  = (i < cnt) ? pw[beg + i] : 0.f;
  }
  __syncthreads();

  const int srow = lane >> 2;
  const int lc   = ((lane & 3) - ((lane >> 3) & 3)) & 3;  // pre-swizzled src
  const long aoff0 = (long)stok[wv*32 +      srow]*HDIM + lc*8;
  const long aoff1 = (long)stok[wv*32 + 16 + srow]*HDIM + lc*8;
  const long boff0 = ((long)e*IDIM + n0 + wv*32 +      srow)*HDIM + lc*8;
  const long boff1 = ((long)e*IDIM + n0 + wv*32 + 16 + srow)*HDIM + lc*8;
  const int dst0 = (wv*32     )*32;
  const int dst1 = (wv*32 + 16)*32;

#define STAGE_A(buf, kk) do {                                   \
    int kl_ = (kk)*32;                                          \
    gld16(Ahi + aoff0 + kl_, &As[buf][0][dst0]);                \
    gld16(Ahi + aoff1 + kl_, &As[buf][0][dst1]);                \
    gld16(Alo + aoff0 + kl_, &As[buf][1][dst0]);                \
    gld16(Alo + aoff1 + kl_, &As[buf][1][dst1]);                \
  } while (0)
#define STAGE_B(buf, kk) do {                                   \
    int kl_ = (kk)*32;                                          \
    gld16(Bhi + boff0 + kl_, &Bs[buf][0][dst0]);                \
    gld16(Bhi + boff1 + kl_, &Bs[buf][0][dst1]);                \
    gld16(Blo + boff0 + kl_, &Bs[buf][1][dst0]);                \
    gld16(Blo + boff1 + kl_, &Bs[buf][1][dst1]);                \
  } while (0)

  const int fl = lane & 15, fg = lane >> 4;
  const int pks = (((fg + (fl >> 1)) & 3) << 3);
  const int wm = wv >> 2, wn = wv & 3;   // 2M x 4N wave grid
  const int arow = wm * 128;
  const int bcol = wn * 64;

  f32x4 acc[8][4];
#pragma unroll
  for (int m = 0; m < 8; m++)
#pragma unroll
    for (int n = 0; n < 4; n++) acc[m][n] = {0.f, 0.f, 0.f, 0.f};

  STAGE_A(0, 0);
  STAGE_B(0, 0);
  __syncthreads();

  int cur = 0;
  for (int kt = 0; kt < HDIM/BK; ++kt) {   // 32 macro-tiles
    const bool st = (kt + 1 < HDIM/BK);
    s16x8 ahf[8], bhi4[4], blo4[4];

    // phase A: issue A(t+1) | read Ahi[8]+Bhi[4]+Blo[4] | 32 MFMA hi*hi
    if (st) STAGE_A(cur^1, kt + 1);
#pragma unroll
    for (int n = 0; n < 4; n++)
      bhi4[n] = *(const s16x8*)&Bs[cur][0][(bcol + n*16 + fl)*32 + pks];
#pragma unroll
    for (int n = 0; n < 4; n++)
      blo4[n] = *(const s16x8*)&Bs[cur][1][(bcol + n*16 + fl)*32 + pks];
#pragma unroll
    for (int i = 0; i < 8; i++)
      ahf[i] = *(const s16x8*)&As[cur][0][(arow + i*16 + fl)*32 + pks];
    __builtin_amdgcn_s_setprio(1);
#pragma unroll
    for (int i = 0; i < 8; i++)
#pragma unroll
      for (int n = 0; n < 4; n++)
        acc[i][n] = __builtin_amdgcn_mfma_f32_16x16x32_bf16(ahf[i], bhi4[n], acc[i][n], 0,0,0);
    __builtin_amdgcn_s_setprio(0);

    // phase B: issue B(t+1) | 32 MFMA hi*lo (regs live, no reads)
    if (st) STAGE_B(cur^1, kt + 1);
    __builtin_amdgcn_s_setprio(1);
#pragma unroll
    for (int i = 0; i < 8; i++)
#pragma unroll
      for (int n = 0; n < 4; n++)
        acc[i][n] = __builtin_amdgcn_mfma_f32_16x16x32_bf16(ahf[i], blo4[n], acc[i][n], 0,0,0);
    __builtin_amdgcn_s_setprio(0);

    // phase C: read Alo[8] (reuse ahf regs) | 32 MFMA lo*hi
#pragma unroll
    for (int i = 0; i < 8; i++)
      ahf[i] = *(const s16x8*)&As[cur][1][(arow + i*16 + fl)*32 + pks];
    __builtin_amdgcn_s_setprio(1);
#pragma unroll
    for (int i = 0; i < 8; i++)
#pragma unroll
      for (int n = 0; n < 4; n++)
        acc[i][n] = __builtin_amdgcn_mfma_f32_16x16x32_bf16(ahf[i], bhi4[n], acc[i][n], 0,0,0);
    __builtin_amdgcn_s_setprio(0);

    __syncthreads();   // drains vmcnt: t+1 landed; everyone done with cur
    cur ^= 1;
  }
#undef STAGE_A
#undef STAGE_B

  // epilogue: C/D map col=lane&15, row=(lane>>4)*4+r  [m89/m91-verified]
#pragma unroll
  for (int m = 0; m < 8; m++)
#pragma unroll
    for (int r = 0; r < 4; r++) {
      int lrow = arow + m*16 + fg*4 + r;
      if (m0 + lrow < cnt) {
        float wt = swt[lrow];
        long ob = (long)stok[lrow]*IDIM + n0 + bcol + fl;
#pragma unroll
        for (int n = 0; n < 4; n++)
          atomicAdd(&out[ob + n*16], wt * acc[m][n][r]);
      }
    }
}

// ===== K6: fused SwiGLU + down-router; writes h as bf16 (RNE) =============
__global__ __launch_bounds__(256) void swiglu_router_bf(
    const float* __restrict__ g, const float* __restrict__ u,
    unsigned short* __restrict__ hb,
    const float* __restrict__ RW,
    int* __restrict__ topi, float* __restrict__ topw) {
  int lane = threadIdx.x & 63;
  int t = blockIdx.x*4 + (threadIdx.x>>6);
  const f32x4* gr = (const f32x4*)(g + (long)t*IDIM);
  const f32x4* ur = (const f32x4*)(u + (long)t*IDIM);
  u16x4*       hr = (u16x4*)(hb + (long)t*IDIM);
  float acc[NEXP];
#pragma unroll
  for (int e = 0; e < NEXP; e++) acc[e] = 0.f;
#pragma unroll
  for (int it = 0; it < IDIM/4/64; it++) {   // 14
    int c4 = it*64 + lane;
    f32x4 gv = gr[c4], uv = ur[c4], hv;
    u16x4 hh;
#pragma unroll
    for (int j = 0; j < 4; j++) {
      float x = gv[j];
      hv[j] = x * uv[j] / (1.f + expf(-x));
      hh[j] = f2bf_rne(hv[j]);
    }
    hr[c4] = hh;
#pragma unroll
    for (int j = 0; j < 4; j++) {
      const float* wr = RW + (long)(c4*4+j)*NEXP;
#pragma unroll
      for (int e = 0; e < NEXP; e++) acc[e] += hv[j]*wr[e];
    }
  }
#pragma unroll
  for (int e = 0; e < NEXP; e++) {
    float v = acc[e];
#pragma unroll
    for (int o = 1; o < 64; o <<= 1) v += __shfl_xor(v, o);
    acc[e] = v;
  }
  if (lane == 0) top2_write(acc, t, topi, topw);
}

// ===== K7: down GEMM, both operands bf16 gld16-staged, dbuf + swizzle =====
__global__ __launch_bounds__(256) void moe_gemm_down_bf(
    const unsigned short* __restrict__ Hb, const unsigned short* __restrict__ Bw,
    const int* __restrict__ offs, const int* __restrict__ ptok,
    const float* __restrict__ pw, float* __restrict__ out)
{
  const int K = IDIM, N = HDIM;
  const int e = blockIdx.z;
  const int beg = offs[e];
  const int cnt = offs[e+1] - beg;
  const int m0 = blockIdx.y * 128;   // NO swizzle
  if (m0 >= cnt) return;
  const int n0 = blockIdx.x * 128;

  __shared__ unsigned short As[2][128*32], Bs[2][128*32];  // 32KB dbuf
  __shared__ int   stok[128];
  __shared__ float swt[128];

  const int tid = threadIdx.x, lane = tid & 63, wv = tid >> 6;  // 4 waves
  if (tid < 128) {
    int i = m0 + tid;
    stok[tid] = ptok[beg + (i < cnt ? i : 0)];
    swt[tid]  = (i < cnt) ? pw[beg + i] : 0.f;
  }
  __syncthreads();

  const int srow = lane >> 2;
  const int lc   = ((lane & 3) - ((lane >> 3) & 3)) & 3;
  const long aoff0 = (long)stok[wv*32 +      srow]*K + lc*8;
  const long aoff1 = (long)stok[wv*32 + 16 + srow]*K + lc*8;
  const long boff0 = ((long)e*N + n0 + wv*32 +      srow)*K + lc*8;
  const long boff1 = ((long)e*N + n0 + wv*32 + 16 + srow)*K + lc*8;
  const int dst0 = (wv*32     )*32;
  const int dst1 = (wv*32 + 16)*32;

#define STAGE(buf, kt) do {                                 \
    int kl_ = (kt)*32;                                      \
    gld16(Hb + aoff0 + kl_, &As[buf][dst0]);                \
    gld16(Hb + aoff1 + kl_, &As[buf][dst1]);                \
    gld16(Bw + boff0 + kl_, &Bs[buf][dst0]);                \
    gld16(Bw + boff1 + kl_, &Bs[buf][dst1]);                \
  } while (0)

  const int fl = lane & 15, fg = lane >> 4;
  const int pks = (((fg + (fl >> 1)) & 3) << 3);
  const int arow = (wv >> 1)*64, bcol = (wv & 1)*64;

  f32x4 acc[4][4];
#pragma unroll
  for (int m = 0; m < 4; m++)
#pragma unroll
    for (int n = 0; n < 4; n++) acc[m][n] = {0.f, 0.f, 0.f, 0.f};

  STAGE(0, 0);
  __syncthreads();

  int cur = 0;
  for (int kt = 0; kt < K/BK; ++kt) {   // 112
    if (kt + 1 < K/BK) STAGE(cur^1, kt + 1);

    s16x8 ahf[4], bhf[4];
#pragma unroll
    for (int i = 0; i < 4; i++) {
      ahf[i] = *(const s16x8*)&As[cur][(arow + i*16 + fl)*32 + pks];
      bhf[i] = *(const s16x8*)&Bs[cur][(bcol + i*16 + fl)*32 + pks];
    }
    __builtin_amdgcn_s_setprio(1);
#pragma unroll
    for (int i = 0; i < 4; i++)
#pragma unroll
      for (int n = 0; n < 4; n++)
        acc[i][n] = __builtin_amdgcn_mfma_f32_16x16x32_bf16(ahf[i], bhf[n], acc[i][n], 0,0,0);
    __builtin_amdgcn_s_setprio(0);

    __syncthreads();
    cur ^= 1;
  }
#undef STAGE

#pragma unroll
  for (int m = 0; m < 4; m++)
#pragma unroll
    for (int r = 0; r < 4; r++) {
      int lrow = arow + m*16 + fg*4 + r;
      if (m0 + lrow < cnt) {
        float wt = swt[lrow];
        long ob = (long)stok[lrow]*N + n0 + bcol + fl;
#pragma unroll
        for (int n = 0; n < 4; n++)
          atomicAdd(&out[ob + n*16], wt * acc[m][n][r]);
      }
    }
}

// ========================== host launcher =================================
// Workspace plan (469.8MB avail; peak ~445.6MB). wd_hi now UN-aliased so all
// three transposes run in ONE upfront dispatch. Remaining aliases:
//   ubuf (f32, 117.4MB) = wg_hi+wg_lo region — memset AFTER gate GEMM.
//   hbuf (bf16, 58.7MB) = wu_lo — written by swiglu AFTER up GEMM.
extern "C" void kernel_launch(void* const* d_in, const int* in_sizes, int n_in,
                              void* d_out, int out_size, void* d_ws, size_t ws_size,
                              hipStream_t stream)
{
  (void)in_sizes; (void)n_in;
  const float* x   = (const float*)d_in[0];
  const float* grt = (const float*)d_in[1];
  const float* gex = (const float*)d_in[2];
  const float* urt = (const float*)d_in[3];
  const float* uex = (const float*)d_in[4];
  const float* drt = (const float*)d_in[5];
  const float* dex = (const float*)d_in[6];
  float* out = (float*)d_out;

  char* base = (char*)d_ws;
  size_t off = 0;
  auto alloc = [&](size_t b) -> void* {
    void* r = base + off;
    off = (off + b + 255) & ~(size_t)255;
    return r;
  };
  const size_t szXH = (size_t)T_TOK*HDIM*2;          // 16.78 MB
  const size_t szW  = (size_t)NEXP*HDIM*IDIM*2;      // 58.72 MB
  const size_t szGI = (size_t)T_TOK*IDIM*4;          // 117.44 MB

  unsigned short* xhi   = (unsigned short*)alloc(szXH);
  unsigned short* xlo   = (unsigned short*)alloc(szXH);
  unsigned short* wg_hi = (unsigned short*)alloc(szW);   // later: ubuf (f32)
  unsigned short* wg_lo = (unsigned short*)alloc(szW);
  unsigned short* wu_hi = (unsigned short*)alloc(szW);
  unsigned short* wu_lo = (unsigned short*)alloc(szW);   // later: hbuf (bf16)
  unsigned short* wd_hi = (unsigned short*)alloc(szW);   // separate (round-12)
  float* gbuf = (float*)alloc(szGI);
  int*   topi_g = (int*)alloc(NPAIR*4);  float* topw_g = (float*)alloc(NPAIR*4);
  int*   topi_u = (int*)alloc(NPAIR*4);  float* topw_u = (float*)alloc(NPAIR*4);
  int*   topi_d = (int*)alloc(NPAIR*4);  float* topw_d = (float*)alloc(NPAIR*4);
  int* offs_g = (int*)alloc(64);
  int* offs_u = (int*)alloc(64);
  int* offs_d = (int*)alloc(64);
  int*   ptok_g = (int*)alloc(NPAIR*4);  float* pw_g = (float*)alloc(NPAIR*4);
  int*   ptok_u = (int*)alloc(NPAIR*4);  float* pw_u = (float*)alloc(NPAIR*4);
  int*   ptok_d = (int*)alloc(NPAIR*4);  float* pw_d = (float*)alloc(NPAIR*4);

  float*          ubuf = (float*)wg_hi;   // spans wg_hi+wg_lo (contiguous)
  unsigned short* hbuf = wu_lo;

  if (off > ws_size) {
    fprintf(stderr, "[moe] ws too small: need %zu bytes, have %zu\n", off, ws_size);
    hipMemsetAsync(d_out, 0, (size_t)out_size*sizeof(float), stream);
    return;
  }

  hipMemsetAsync(gbuf, 0, szGI, stream);
  hipMemsetAsync(d_out, 0, (size_t)out_size*sizeof(float), stream);

  // one dispatch: gate/up/down weight transpose+split
  transpose_split3<<<dim3(IDIM/32, HDIM/32, 3*NEXP), dim3(8,32), 0, stream>>>(
      gex, wg_hi, wg_lo, uex, wu_hi, wu_lo, dex, wd_hi);
  split_router<<<T_TOK/4, 256, 0, stream>>>(x, grt, urt, xhi, xlo,
                                            topi_g, topw_g, topi_u, topw_u);
  build_perm2<<<2*NEXP, 256, 0, stream>>>(topi_g, topw_g, offs_g, ptok_g, pw_g,
                                          topi_u, topw_u, offs_u, ptok_u, pw_u);

  // gate GEMM (last reader of wg region)
  moe_gemm3_mt<<<dim3(IDIM/256, 32, NEXP), 512, 0, stream>>>(
      xhi, xlo, wg_hi, wg_lo, offs_g, ptok_g, pw_g, gbuf);

  // wg region dead -> ubuf
  hipMemsetAsync(ubuf, 0, szGI, stream);
  moe_gemm3_mt<<<dim3(IDIM/256, 32, NEXP), 512, 0, stream>>>(
      xhi, xlo, wu_hi, wu_lo, offs_u, ptok_u, pw_u, ubuf);

  // fused: h = silu(g)*u -> bf16 hbuf (aliases wu_lo, dead after up GEMM)
  // + down-router top2 on exact f32 h
  swiglu_router_bf<<<T_TOK/4, 256, 0, stream>>>(gbuf, ubuf, hbuf, drt, topi_d, topw_d);
  build_perm<<<NEXP, 256, 0, stream>>>(topi_d, topw_d, offs_d, ptok_d, pw_d);

  moe_gemm_down_bf<<<dim3(HDIM/128, 64, NEXP), 256, 0, stream>>>(
      hbuf, wd_hi, offs_d, ptok_d, pw_d, out);
}